// Round 2
// baseline (1179.072 us; speedup 1.0000x reference)
//
#include <hip/hip_runtime.h>
#include <hip/hip_bf16.h>

typedef unsigned short u16;
typedef __attribute__((ext_vector_type(8))) short bf16x8;
typedef __attribute__((ext_vector_type(8))) unsigned short us8;
typedef __attribute__((ext_vector_type(4))) float f32x4;

#define T_Q 32
#define T_K 48
#define NB 64
#define HDIM 1024
#define MASK_FILL -65504.0f

__device__ __forceinline__ float bf2f(u16 v){
  union { unsigned u; float f; } x; x.u = ((unsigned)v) << 16; return x.f;
}
__device__ __forceinline__ u16 f2bf(float f){
  union { float f; unsigned u; } x; x.f = f;
  return (u16)((x.u + 0x7FFFu + ((x.u >> 16) & 1u)) >> 16);
}
__device__ __forceinline__ float sigm(float x){ return 1.f / (1.f + __expf(-x)); }
__device__ __forceinline__ float tanh_f(float x){
  float e = __expf(2.f * x);
  return 1.f - 2.f / (e + 1.f);          // graceful at +/-inf
}

// ---------------- prep kernels ----------------

__global__ void conv_f2b(const float* __restrict__ s, u16* __restrict__ d){
  size_t i = ((size_t)blockIdx.x * 256 + threadIdx.x) * 4;
  float4 v = *(const float4*)(s + i);
  ushort4 o; o.x = f2bf(v.x); o.y = f2bf(v.y); o.z = f2bf(v.z); o.w = f2bf(v.w);
  *(ushort4*)(d + i) = o;
}

__global__ void gather_x(const int* __restrict__ tok, const float* __restrict__ emb,
                         u16* __restrict__ x){
  int r = blockIdx.x;                      // r = t*64 + b
  int token = tok[r];
  float4 v = ((const float4*)(emb + (size_t)token * HDIM))[threadIdx.x];
  ushort4 o; o.x = f2bf(v.x); o.y = f2bf(v.y); o.z = f2bf(v.z); o.w = f2bf(v.w);
  ((ushort4*)(x + (size_t)r * HDIM))[threadIdx.x] = o;
}

__global__ void make_keys(const float* __restrict__ a, const float* __restrict__ b,
                          u16* __restrict__ o){
  size_t i = ((size_t)blockIdx.x * 256 + threadIdx.x) * 4;
  float4 va = *(const float4*)(a + i);
  float4 vb = *(const float4*)(b + i);
  ushort4 vo;
  vo.x = f2bf(va.x + vb.x);
  vo.y = f2bf(va.y + vb.y);
  vo.z = f2bf(va.z + vb.z);
  vo.w = f2bf(va.w + vb.w);
  *(ushort4*)(o + i) = vo;
}

__global__ void prep_small(const float* __restrict__ vatt, const float* __restrict__ ns,
                           const float* __restrict__ bih,  const float* __restrict__ bhh,
                           const float* __restrict__ nb,
                           float* __restrict__ vhat, float* __restrict__ bias_sum,
                           float* __restrict__ nbias){
  __shared__ float wred[4];
  int t = threadIdx.x, lane = t & 63, w = t >> 6;
  float vv[4]; float s = 0.f;
  #pragma unroll
  for (int j = 0; j < 4; j++){ vv[j] = vatt[t*4 + j]; s += vv[j]*vv[j]; }
  #pragma unroll
  for (int m = 32; m >= 1; m >>= 1) s += __shfl_xor(s, m);
  if (lane == 0) wred[w] = s;
  __syncthreads();
  float tot = wred[0] + wred[1] + wred[2] + wred[3];
  float scale = ns[0] / sqrtf(tot);
  #pragma unroll
  for (int j = 0; j < 4; j++) vhat[t*4 + j] = vv[j] * scale;
  #pragma unroll
  for (int j = 0; j < 16; j++){ int i = t + 256*j; bias_sum[i] = bih[i] + bhh[i]; }
  #pragma unroll
  for (int j = 0; j < 4; j++){ int i = t + 256*j; nbias[i] = nb[i]; }
}

// ---------------- generic bf16 GEMM: C[M][N] = A[M][K] * W[N][K]^T + bias ----------------
// OB=1 -> bf16 output, OB=0 -> f32 output.

template<int OB>
__global__ __launch_bounds__(256) void gemm_bf16(
  const u16* __restrict__ A, const u16* __restrict__ W,
  const float* __restrict__ bias, void* __restrict__ Cv,
  int M, int N, int K)
{
  __shared__ __align__(16) u16 As[4][66][8];   // [kc][row][8], kc-stride 1056B
  __shared__ __align__(16) u16 Bs[4][66][8];
  const int t = threadIdx.x;
  const int m0 = blockIdx.y * 64, n0 = blockIdx.x * 64;
  const int lane = t & 63, w = t >> 6;
  const int wm = (w >> 1) * 32, wn = (w & 1) * 32;
  const int lr = lane & 15, g = lane >> 4;
  const int lrow = t >> 2, lkc = t & 3;
  f32x4 acc00 = {0,0,0,0}, acc01 = {0,0,0,0}, acc10 = {0,0,0,0}, acc11 = {0,0,0,0};
  const u16* aptr = A + (size_t)(m0 + lrow) * K + lkc * 8;
  const u16* wptr = W + (size_t)(n0 + lrow) * K + lkc * 8;
  for (int k0 = 0; k0 < K; k0 += 32){
    *(bf16x8*)(&As[lkc][lrow][0]) = *(const bf16x8*)(aptr + k0);
    *(bf16x8*)(&Bs[lkc][lrow][0]) = *(const bf16x8*)(wptr + k0);
    __syncthreads();
    bf16x8 a0 = *(const bf16x8*)(&As[g][wm      + lr][0]);
    bf16x8 a1 = *(const bf16x8*)(&As[g][wm + 16 + lr][0]);
    bf16x8 b0 = *(const bf16x8*)(&Bs[g][wn      + lr][0]);
    bf16x8 b1 = *(const bf16x8*)(&Bs[g][wn + 16 + lr][0]);
    acc00 = __builtin_amdgcn_mfma_f32_16x16x32_bf16(a0, b0, acc00, 0, 0, 0);
    acc01 = __builtin_amdgcn_mfma_f32_16x16x32_bf16(a0, b1, acc01, 0, 0, 0);
    acc10 = __builtin_amdgcn_mfma_f32_16x16x32_bf16(a1, b0, acc10, 0, 0, 0);
    acc11 = __builtin_amdgcn_mfma_f32_16x16x32_bf16(a1, b1, acc11, 0, 0, 0);
    __syncthreads();
  }
  // C/D layout: col = lane&15, row = (lane>>4)*4 + reg   [m89-verified]
  const int rb = m0 + wm + g * 4;
  const int cb = n0 + wn + lr;
  float bv0 = bias ? bias[cb]      : 0.f;
  float bv1 = bias ? bias[cb + 16] : 0.f;
  #pragma unroll
  for (int r = 0; r < 4; r++){
    float v00 = acc00[r] + bv0, v01 = acc01[r] + bv1;
    float v10 = acc10[r] + bv0, v11 = acc11[r] + bv1;
    if (OB){
      u16* C = (u16*)Cv;
      C[(size_t)(rb + r)      * N + cb]      = f2bf(v00);
      C[(size_t)(rb + r)      * N + cb + 16] = f2bf(v01);
      C[(size_t)(rb + 16 + r) * N + cb]      = f2bf(v10);
      C[(size_t)(rb + 16 + r) * N + cb + 16] = f2bf(v11);
    } else {
      float* C = (float*)Cv;
      C[(size_t)(rb + r)      * N + cb]      = v00;
      C[(size_t)(rb + r)      * N + cb + 16] = v01;
      C[(size_t)(rb + 16 + r) * N + cb]      = v10;
      C[(size_t)(rb + 16 + r) * N + cb + 16] = v11;
    }
  }
}

// ---------------- LSTM step: gates = xp[t] + h * Whh^T, then pointwise ----------------
// block = 32 h-cols; wave w computes gate w's 64x32 tile; combine via LDS union.

__global__ __launch_bounds__(256) void lstm_step(
  const u16* __restrict__ hprev, const u16* __restrict__ Whh,
  const u16* __restrict__ xp_t, float* __restrict__ cbuf,
  u16* __restrict__ hnext, u16* __restrict__ qbuf, float* __restrict__ out0,
  int tstep)
{
  __shared__ __align__(16) union U {
    struct { u16 As[4][66][8]; u16 Bs[4][4][34][8]; } tl;  // A: 64x32, B: 4 gates x 32x32
    float gl[4][64][32];
  } sh;
  const int t = threadIdx.x;
  const int hcol0 = blockIdx.x * 32;
  const int lane = t & 63, w = t >> 6;
  const int lr = lane & 15, g = lane >> 4;
  const int lrow = t >> 2, lkc = t & 3;
  f32x4 acc[4][2];
  #pragma unroll
  for (int i = 0; i < 4; i++) for (int j = 0; j < 2; j++) acc[i][j] = (f32x4){0,0,0,0};

  for (int k0 = 0; k0 < HDIM; k0 += 32){
    *(bf16x8*)(&sh.tl.As[lkc][lrow][0]) =
      *(const bf16x8*)(hprev + (size_t)lrow * HDIM + k0 + lkc * 8);
    #pragma unroll
    for (int i = 0; i < 2; i++){
      int c = t + 256 * i;                 // 512 chunks of 8 bf16
      int gate = c >> 7, rem = c & 127, rr = rem >> 2, kc = rem & 3;
      *(bf16x8*)(&sh.tl.Bs[gate][kc][rr][0]) =
        *(const bf16x8*)(Whh + (size_t)(gate * HDIM + hcol0 + rr) * HDIM + k0 + kc * 8);
    }
    __syncthreads();
    bf16x8 b0 = *(const bf16x8*)(&sh.tl.Bs[w][g][lr][0]);
    bf16x8 b1 = *(const bf16x8*)(&sh.tl.Bs[w][g][16 + lr][0]);
    #pragma unroll
    for (int mi = 0; mi < 4; mi++){
      bf16x8 af = *(const bf16x8*)(&sh.tl.As[g][mi * 16 + lr][0]);
      acc[mi][0] = __builtin_amdgcn_mfma_f32_16x16x32_bf16(af, b0, acc[mi][0], 0, 0, 0);
      acc[mi][1] = __builtin_amdgcn_mfma_f32_16x16x32_bf16(af, b1, acc[mi][1], 0, 0, 0);
    }
    __syncthreads();
  }
  #pragma unroll
  for (int mi = 0; mi < 4; mi++)
    #pragma unroll
    for (int ni = 0; ni < 2; ni++)
      #pragma unroll
      for (int r = 0; r < 4; r++)
        sh.gl[w][mi * 16 + g * 4 + r][ni * 16 + lr] = acc[mi][ni][r];
  __syncthreads();

  #pragma unroll
  for (int j = 0; j < 8; j++){
    int e = t + 256 * j;                   // 2048 = 64 batch x 32 cols
    int b = e >> 5, hc = e & 31;
    int col = hcol0 + hc;
    const u16* xr = xp_t + (size_t)b * 4096;
    float ig = sh.gl[0][b][hc] + bf2f(xr[col]);
    float fg = sh.gl[1][b][hc] + bf2f(xr[1024 + col]);
    float gg = sh.gl[2][b][hc] + bf2f(xr[2048 + col]);
    float og = sh.gl[3][b][hc] + bf2f(xr[3072 + col]);
    int cidx = b * HDIM + col;
    float cn = sigm(fg) * cbuf[cidx] + sigm(ig) * tanh_f(gg);
    cbuf[cidx] = cn;
    float h = sigm(og) * tanh_f(cn);
    hnext[cidx] = f2bf(h);
    qbuf[(size_t)(b * T_Q + tstep) * HDIM + col] = f2bf(h);
    out0[(size_t)(tstep * NB + b) * HDIM + col] = h;
  }
}

// ---------------- fused attention: scores -> mask -> softmax -> context ----------------
// block per (b,q). wave w handles keys k in [w*12, w*12+12). lane owns h = lane*16..+15.

__global__ __launch_bounds__(256) void attn_fused(
  const float* __restrict__ aq, const u16* __restrict__ ak,
  const float* __restrict__ vhat, const u16* __restrict__ keys,
  const int* __restrict__ lens, float* __restrict__ out1)
{
  int b = blockIdx.x >> 5, q = blockIdx.x & 31;
  int t = threadIdx.x, lane = t & 63, w = t >> 6;
  __shared__ float sc[T_K];
  __shared__ float ps[T_K];
  int len = lens[b];
  float aqr[16], vh[16];
  const float* aqp = aq + (size_t)(b * T_Q + q) * HDIM + lane * 16;
  const float* vp  = vhat + lane * 16;
  #pragma unroll
  for (int j = 0; j < 4; j++){
    float4 v0 = ((const float4*)aqp)[j];
    float4 v1 = ((const float4*)vp)[j];
    aqr[j*4+0] = v0.x; aqr[j*4+1] = v0.y; aqr[j*4+2] = v0.z; aqr[j*4+3] = v0.w;
    vh[j*4+0]  = v1.x; vh[j*4+1]  = v1.y; vh[j*4+2]  = v1.z; vh[j*4+3]  = v1.w;
  }

  for (int kk = 0; kk < 12; kk++){
    int k = w * 12 + kk;
    const u16* akp = ak + (size_t)(k * NB + b) * HDIM + lane * 16;
    us8 a0 = *(const us8*)(akp);
    us8 a1 = *(const us8*)(akp + 8);
    float p = 0.f;
    #pragma unroll
    for (int j = 0; j < 8; j++){
      p += tanh_f(aqr[j]     + bf2f(a0[j])) * vh[j];
      p += tanh_f(aqr[8 + j] + bf2f(a1[j])) * vh[8 + j];
    }
    #pragma unroll
    for (int m = 32; m >= 1; m >>= 1) p += __shfl_xor(p, m);
    if (lane == 0) sc[k] = (k < len) ? p : MASK_FILL;
  }
  __syncthreads();
  float mx = -3.0e38f;
  #pragma unroll
  for (int k = 0; k < T_K; k++) mx = fmaxf(mx, sc[k]);
  if (t < T_K) ps[t] = (t < len) ? __expf(sc[t] - mx) : 0.f;
  __syncthreads();
  float den = 0.f;
  #pragma unroll
  for (int k = 0; k < T_K; k++) den += ps[k];
  float rden = 1.f / den;

  float c0 = 0.f, c1 = 0.f, c2 = 0.f, c3 = 0.f;
  for (int k = 0; k < len; k++){
    float pk = ps[k];
    ushort4 kv = *(const ushort4*)(keys + (size_t)(k * NB + b) * HDIM + t * 4);
    c0 += pk * bf2f(kv.x); c1 += pk * bf2f(kv.y);
    c2 += pk * bf2f(kv.z); c3 += pk * bf2f(kv.w);
  }
  size_t o = (size_t)(q * NB + b) * HDIM + t * 4;
  out1[o + 0] = c0 * rden;
  out1[o + 1] = c1 * rden;
  out1[o + 2] = c2 * rden;
  out1[o + 3] = c3 * rden;
}

// ---------------- launch ----------------

extern "C" void kernel_launch(void* const* d_in, const int* in_sizes, int n_in,
                              void* d_out, int out_size, void* d_ws, size_t ws_size,
                              hipStream_t stream)
{
  const float* in1  = (const float*)d_in[0];   // input1
  const float* in0  = (const float*)d_in[1];   // input0
  const int*   lens = (const int*)d_in[2];     // input2
  const int*   toks = (const int*)d_in[3];     // input3
  const float* emb  = (const float*)d_in[4];
  const float* Wih  = (const float*)d_in[5];
  const float* Whh  = (const float*)d_in[6];
  const float* bih  = (const float*)d_in[7];
  const float* bhh  = (const float*)d_in[8];
  const float* Wq   = (const float*)d_in[9];
  const float* Wk   = (const float*)d_in[10];
  const float* vatt = (const float*)d_in[11];
  const float* ns   = (const float*)d_in[12];
  const float* nbb  = (const float*)d_in[13];

  char* p = (char*)d_ws;
  u16* x_bf    = (u16*)p;   p += (size_t)2048 * 1024 * 2;   // 4 MB
  u16* keys_bf = (u16*)p;   p += (size_t)3072 * 1024 * 2;   // 6 MB
  u16* h0      = (u16*)p;   p += (size_t)64 * 1024 * 2;
  u16* h1      = (u16*)p;   p += (size_t)64 * 1024 * 2;
  u16* qbuf    = (u16*)p;   p += (size_t)2048 * 1024 * 2;   // 4 MB
  u16* xp      = (u16*)p;   p += (size_t)2048 * 4096 * 2;   // 16 MB (dead after LSTM)
  float* cbuf  = (float*)p; p += (size_t)64 * 1024 * 4;
  float* vhat  = (float*)p; p += 1024 * 4;
  float* bsum  = (float*)p; p += 4096 * 4;
  float* nbf   = (float*)p; p += 1024 * 4;
  u16* ak      = (u16*)p;   p += (size_t)3072 * 1024 * 2;   // 6 MB
  u16* Wih_bf  = (u16*)p;   p += (size_t)4096 * 1024 * 2;   // 8 MB
  u16* Whh_bf  = (u16*)p;   p += (size_t)4096 * 1024 * 2;   // 8 MB
  u16* Wq_bf   = (u16*)p;   p += (size_t)1024 * 1024 * 2;   // 2 MB
  u16* Wk_bf   = (u16*)p;   p += (size_t)1024 * 1024 * 2;   // 2 MB
  float* aq    = (float*)xp;   // 8 MB, aliases xp (xp fully consumed before aq GEMM)

  float* out0 = (float*)d_out;
  float* out1 = out0 + (size_t)T_Q * NB * HDIM;

  hipMemsetAsync(h0,   0, (size_t)64 * 1024 * 2, stream);
  hipMemsetAsync(cbuf, 0, (size_t)64 * 1024 * 4, stream);

  conv_f2b<<<4096, 256, 0, stream>>>(Wih, Wih_bf);
  conv_f2b<<<4096, 256, 0, stream>>>(Whh, Whh_bf);
  conv_f2b<<<1024, 256, 0, stream>>>(Wq,  Wq_bf);
  conv_f2b<<<1024, 256, 0, stream>>>(Wk,  Wk_bf);
  gather_x<<<2048, 256, 0, stream>>>(toks, emb, x_bf);
  make_keys<<<3072, 256, 0, stream>>>(in1, in0, keys_bf);
  prep_small<<<1, 256, 0, stream>>>(vatt, ns, bih, bhh, nbb, vhat, bsum, nbf);

  // xp = x * Wih^T + (bih + bhh) : M=2048, N=4096, K=1024 -> bf16
  gemm_bf16<1><<<dim3(64, 32), 256, 0, stream>>>(x_bf, Wih_bf, bsum, xp, 2048, 4096, 1024);
  // ak = keys * Wk^T + norm_bias : M=3072, N=1024, K=1024 -> bf16
  gemm_bf16<1><<<dim3(16, 48), 256, 0, stream>>>(keys_bf, Wk_bf, nbf, ak, 3072, 1024, 1024);

  for (int tstep = 0; tstep < T_Q; tstep++){
    const u16* hp = (tstep & 1) ? h1 : h0;
    u16* hn       = (tstep & 1) ? h0 : h1;
    lstm_step<<<32, 256, 0, stream>>>(hp, Whh_bf, xp + (size_t)tstep * 64 * 4096,
                                      cbuf, hn, qbuf, out0, tstep);
  }

  // aq = q * Wq^T : M=2048, N=1024, K=1024 -> f32 (writes over xp region, now dead)
  gemm_bf16<0><<<dim3(16, 32), 256, 0, stream>>>(qbuf, Wq_bf, nullptr, aq, 2048, 1024, 1024);

  attn_fused<<<2048, 256, 0, stream>>>(aq, ak, vhat, keys_bf, lens, out1);
}

// Round 3
// 807.772 us; speedup vs baseline: 1.4597x; 1.4597x over previous
//
#include <hip/hip_runtime.h>
#include <hip/hip_bf16.h>

typedef unsigned short u16;
typedef __attribute__((ext_vector_type(8))) short bf16x8;
typedef __attribute__((ext_vector_type(8))) unsigned short us8;
typedef __attribute__((ext_vector_type(4))) float f32x4;

#define T_Q 32
#define T_K 48
#define NB 64
#define HDIM 1024
#define MASK_FILL -65504.0f
#define LSTM_BLOCKS 64

__device__ __forceinline__ float bf2f(u16 v){
  union { unsigned u; float f; } x; x.u = ((unsigned)v) << 16; return x.f;
}
__device__ __forceinline__ u16 f2bf(float f){
  union { float f; unsigned u; } x; x.f = f;
  return (u16)((x.u + 0x7FFFu + ((x.u >> 16) & 1u)) >> 16);
}
// rcp-based (no fp32 div sequence): v_rcp_f32 is ~1ulp, fine at 2% threshold
__device__ __forceinline__ float sigm(float x){
  return __builtin_amdgcn_rcpf(1.f + __expf(-x));
}
__device__ __forceinline__ float tanh_f(float x){
  float e = __expf(2.f * x);
  return fmaf(-2.f, __builtin_amdgcn_rcpf(e + 1.f), 1.f);  // graceful at +/-inf
}

// ---------------- prep kernels ----------------

__global__ void conv_f2b(const float* __restrict__ s, u16* __restrict__ d){
  size_t i = ((size_t)blockIdx.x * 256 + threadIdx.x) * 4;
  float4 v = *(const float4*)(s + i);
  ushort4 o; o.x = f2bf(v.x); o.y = f2bf(v.y); o.z = f2bf(v.z); o.w = f2bf(v.w);
  *(ushort4*)(d + i) = o;
}

__global__ void gather_x(const int* __restrict__ tok, const float* __restrict__ emb,
                         u16* __restrict__ x){
  int r = blockIdx.x;                      // r = t*64 + b
  int token = tok[r];
  float4 v = ((const float4*)(emb + (size_t)token * HDIM))[threadIdx.x];
  ushort4 o; o.x = f2bf(v.x); o.y = f2bf(v.y); o.z = f2bf(v.z); o.w = f2bf(v.w);
  ((ushort4*)(x + (size_t)r * HDIM))[threadIdx.x] = o;
}

__global__ void make_keys(const float* __restrict__ a, const float* __restrict__ b,
                          u16* __restrict__ o){
  size_t i = ((size_t)blockIdx.x * 256 + threadIdx.x) * 4;
  float4 va = *(const float4*)(a + i);
  float4 vb = *(const float4*)(b + i);
  ushort4 vo;
  vo.x = f2bf(va.x + vb.x);
  vo.y = f2bf(va.y + vb.y);
  vo.z = f2bf(va.z + vb.z);
  vo.w = f2bf(va.w + vb.w);
  *(ushort4*)(o + i) = vo;
}

__global__ void prep_small(const float* __restrict__ vatt, const float* __restrict__ ns,
                           const float* __restrict__ nb,
                           float* __restrict__ vhat, float* __restrict__ nbias){
  __shared__ float wred[4];
  int t = threadIdx.x, lane = t & 63, w = t >> 6;
  float vv[4]; float s = 0.f;
  #pragma unroll
  for (int j = 0; j < 4; j++){ vv[j] = vatt[t*4 + j]; s += vv[j]*vv[j]; }
  #pragma unroll
  for (int m = 32; m >= 1; m >>= 1) s += __shfl_xor(s, m);
  if (lane == 0) wred[w] = s;
  __syncthreads();
  float tot = wred[0] + wred[1] + wred[2] + wred[3];
  float scale = ns[0] / sqrtf(tot);
  #pragma unroll
  for (int j = 0; j < 4; j++) vhat[t*4 + j] = vv[j] * scale;
  #pragma unroll
  for (int j = 0; j < 4; j++){ int i = t + 256*j; nbias[i] = nb[i]; }
}

__global__ void prep_bsum(const float* __restrict__ bih, const float* __restrict__ bhh,
                          float* __restrict__ bias_sum){
  int i = blockIdx.x * 256 + threadIdx.x;
  bias_sum[i] = bih[i] + bhh[i];
}

// ---------------- generic bf16 GEMM: C[M][N] = A[M][K] * W[N][K]^T + bias ----------------
// OB=1 -> bf16 output, OB=0 -> f32 output.

template<int OB>
__global__ __launch_bounds__(256) void gemm_bf16(
  const u16* __restrict__ A, const u16* __restrict__ W,
  const float* __restrict__ bias, void* __restrict__ Cv,
  int M, int N, int K)
{
  __shared__ __align__(16) u16 As[4][66][8];   // [kc][row][8], kc-stride 1056B
  __shared__ __align__(16) u16 Bs[4][66][8];
  const int t = threadIdx.x;
  const int m0 = blockIdx.y * 64, n0 = blockIdx.x * 64;
  const int lane = t & 63, w = t >> 6;
  const int wm = (w >> 1) * 32, wn = (w & 1) * 32;
  const int lr = lane & 15, g = lane >> 4;
  const int lrow = t >> 2, lkc = t & 3;
  f32x4 acc00 = {0,0,0,0}, acc01 = {0,0,0,0}, acc10 = {0,0,0,0}, acc11 = {0,0,0,0};
  const u16* aptr = A + (size_t)(m0 + lrow) * K + lkc * 8;
  const u16* wptr = W + (size_t)(n0 + lrow) * K + lkc * 8;
  for (int k0 = 0; k0 < K; k0 += 32){
    *(bf16x8*)(&As[lkc][lrow][0]) = *(const bf16x8*)(aptr + k0);
    *(bf16x8*)(&Bs[lkc][lrow][0]) = *(const bf16x8*)(wptr + k0);
    __syncthreads();
    bf16x8 a0 = *(const bf16x8*)(&As[g][wm      + lr][0]);
    bf16x8 a1 = *(const bf16x8*)(&As[g][wm + 16 + lr][0]);
    bf16x8 b0 = *(const bf16x8*)(&Bs[g][wn      + lr][0]);
    bf16x8 b1 = *(const bf16x8*)(&Bs[g][wn + 16 + lr][0]);
    acc00 = __builtin_amdgcn_mfma_f32_16x16x32_bf16(a0, b0, acc00, 0, 0, 0);
    acc01 = __builtin_amdgcn_mfma_f32_16x16x32_bf16(a0, b1, acc01, 0, 0, 0);
    acc10 = __builtin_amdgcn_mfma_f32_16x16x32_bf16(a1, b0, acc10, 0, 0, 0);
    acc11 = __builtin_amdgcn_mfma_f32_16x16x32_bf16(a1, b1, acc11, 0, 0, 0);
    __syncthreads();
  }
  // C/D layout: col = lane&15, row = (lane>>4)*4 + reg   [m89-verified]
  const int rb = m0 + wm + g * 4;
  const int cb = n0 + wn + lr;
  float bv0 = bias ? bias[cb]      : 0.f;
  float bv1 = bias ? bias[cb + 16] : 0.f;
  #pragma unroll
  for (int r = 0; r < 4; r++){
    float v00 = acc00[r] + bv0, v01 = acc01[r] + bv1;
    float v10 = acc10[r] + bv0, v11 = acc11[r] + bv1;
    if (OB){
      u16* C = (u16*)Cv;
      C[(size_t)(rb + r)      * N + cb]      = f2bf(v00);
      C[(size_t)(rb + r)      * N + cb + 16] = f2bf(v01);
      C[(size_t)(rb + 16 + r) * N + cb]      = f2bf(v10);
      C[(size_t)(rb + 16 + r) * N + cb + 16] = f2bf(v11);
    } else {
      float* C = (float*)Cv;
      C[(size_t)(rb + r)      * N + cb]      = v00;
      C[(size_t)(rb + r)      * N + cb + 16] = v01;
      C[(size_t)(rb + 16 + r) * N + cb]      = v10;
      C[(size_t)(rb + 16 + r) * N + cb + 16] = v11;
    }
  }
}

// ---------------- persistent LSTM ----------------
// 64 blocks x 512 threads. Block j owns h-cols [j*16, j*16+16) for all 4 gates.
// Whh slice (64 rows x 1024 K, f32->bf16) resident in LDS across all 32 steps.
// c-state in registers (2 cells/thread). One device-scope barrier per step.
// LDS: wlds[4][32][16][32] bf16 (128KB) + gl[4][64][16] f32 (16KB) = 144KB -> 1 block/CU.

__global__ __launch_bounds__(512, 1) void lstm_persistent(
  const float* __restrict__ Whh, const u16* __restrict__ xp,
  u16* __restrict__ hA, u16* __restrict__ hB,
  u16* __restrict__ qbuf, float* __restrict__ out0,
  int* __restrict__ bar)
{
  extern __shared__ char smem[];
  u16*  wlds = (u16*)smem;                    // [4][32][16][32] bf16
  float* gl  = (float*)(smem + 131072);       // [4][64][16] f32

  const int tid = threadIdx.x;
  const int c0 = blockIdx.x * 16;
  const int lane = tid & 63, w = tid >> 6;    // 8 waves
  const int gate = w & 3, msub = w >> 2;      // wave -> (gate, m-half)
  const int lr = lane & 15, g = lane >> 4;

  // ---- one-time: Whh slice f32 -> bf16 -> LDS ----
  #pragma unroll
  for (int i = 0; i < 16; i++){
    int e = (i * 512 + tid) * 8;               // element in 64x1024 slice
    int R = e >> 10, k = e & 1023;
    int gg = R >> 4, rr = R & 15, tt = k >> 5, kk = k & 31;
    const float* src = Whh + (size_t)((gg << 10) + c0 + rr) * 1024 + k;
    float4 v0 = *(const float4*)(src);
    float4 v1 = *(const float4*)(src + 4);
    u16* dst = wlds + (((gg * 32 + tt) * 16 + rr) * 32 + kk);
    ushort4 o0, o1;
    o0.x = f2bf(v0.x); o0.y = f2bf(v0.y); o0.z = f2bf(v0.z); o0.w = f2bf(v0.w);
    o1.x = f2bf(v1.x); o1.y = f2bf(v1.y); o1.z = f2bf(v1.z); o1.w = f2bf(v1.w);
    *(ushort4*)dst = o0; *(ushort4*)(dst + 4) = o1;
  }
  __syncthreads();

  // pointwise ownership: 2 cells/thread
  const int pb = (tid * 2) >> 4;               // batch 0..63
  const int pc = (tid * 2) & 15;               // col pair base (even)
  float c_state0 = 0.f, c_state1 = 0.f;

  const int arow = msub * 32 + lr;             // batch rows for this wave's m-tiles

  for (int step = 0; step < T_Q; step++){
    const u16* hprev = (step & 1) ? hB : hA;
    u16* hnext       = (step & 1) ? hA : hB;
    f32x4 acc0 = {0,0,0,0}, acc1 = {0,0,0,0};

    if (step > 0){
      const u16* base0 = hprev + (size_t)arow * HDIM + g * 8;
      const u16* base1 = base0 + 16 * HDIM;
      bf16x8 a0[4], a1[4];
      #pragma unroll
      for (int p = 0; p < 3; p++){
        a0[p] = *(const bf16x8*)(base0 + p * 32);
        a1[p] = *(const bf16x8*)(base1 + p * 32);
      }
      #pragma unroll
      for (int t = 0; t < 32; t++){
        if (t < 29){
          a0[(t + 3) & 3] = *(const bf16x8*)(base0 + (t + 3) * 32);
          a1[(t + 3) & 3] = *(const bf16x8*)(base1 + (t + 3) * 32);
        }
        bf16x8 bfr = *(const bf16x8*)(wlds + ((gate * 32 + t) * 16 + lr) * 32 + g * 8);
        acc0 = __builtin_amdgcn_mfma_f32_16x16x32_bf16(a0[t & 3], bfr, acc0, 0, 0, 0);
        acc1 = __builtin_amdgcn_mfma_f32_16x16x32_bf16(a1[t & 3], bfr, acc1, 0, 0, 0);
      }
    }

    // gate preacts -> LDS exchange. C/D: col=lane&15, row=(lane>>4)*4+reg
    #pragma unroll
    for (int r = 0; r < 4; r++){
      gl[(gate * 64 + msub * 32 +      g * 4 + r) * 16 + lr] = acc0[r];
      gl[(gate * 64 + msub * 32 + 16 + g * 4 + r) * 16 + lr] = acc1[r];
    }
    __syncthreads();

    // pointwise: 2 cells (pb, pc) (pb, pc+1)
    const u16* xr = xp + ((size_t)(step * NB + pb)) * 4096 + c0 + pc;
    float hout0, hout1; u16 hb0, hb1;
    {
      float ig = gl[(0 * 64 + pb) * 16 + pc] + bf2f(xr[0]);
      float fg = gl[(1 * 64 + pb) * 16 + pc] + bf2f(xr[1024]);
      float gg = gl[(2 * 64 + pb) * 16 + pc] + bf2f(xr[2048]);
      float og = gl[(3 * 64 + pb) * 16 + pc] + bf2f(xr[3072]);
      float cn = sigm(fg) * c_state0 + sigm(ig) * tanh_f(gg);
      c_state0 = cn;
      hout0 = sigm(og) * tanh_f(cn); hb0 = f2bf(hout0);
    }
    {
      float ig = gl[(0 * 64 + pb) * 16 + pc + 1] + bf2f(xr[1]);
      float fg = gl[(1 * 64 + pb) * 16 + pc + 1] + bf2f(xr[1025]);
      float gg = gl[(2 * 64 + pb) * 16 + pc + 1] + bf2f(xr[2049]);
      float og = gl[(3 * 64 + pb) * 16 + pc + 1] + bf2f(xr[3073]);
      float cn = sigm(fg) * c_state1 + sigm(ig) * tanh_f(gg);
      c_state1 = cn;
      hout1 = sigm(og) * tanh_f(cn); hb1 = f2bf(hout1);
    }
    ushort2 hh; hh.x = hb0; hh.y = hb1;
    *(ushort2*)(hnext + (size_t)pb * HDIM + c0 + pc) = hh;
    *(ushort2*)(qbuf + ((size_t)pb * T_Q + step) * HDIM + c0 + pc) = hh;
    float2 ho; ho.x = hout0; ho.y = hout1;
    *(float2*)(out0 + ((size_t)(step * NB + pb)) * HDIM + c0 + pc) = ho;

    // ---- grid barrier (monotonic counter; release-wbl2 / acquire-inv) ----
    __syncthreads();                           // drains vmcnt -> stores in L2
    if (tid == 0){
      __threadfence();                         // release: L2 writeback
      atomicAdd(bar, 1);
      const int target = LSTM_BLOCKS * (step + 1);
      while (__hip_atomic_load(bar, __ATOMIC_RELAXED, __HIP_MEMORY_SCOPE_AGENT) < target)
        __builtin_amdgcn_s_sleep(2);
      __threadfence();                         // acquire: L2 invalidate
    }
    __syncthreads();
  }
}

// ---------------- fused attention: scores -> mask -> softmax -> context ----------------

__global__ __launch_bounds__(256) void attn_fused(
  const float* __restrict__ aq, const u16* __restrict__ ak,
  const float* __restrict__ vhat, const u16* __restrict__ keys,
  const int* __restrict__ lens, float* __restrict__ out1)
{
  int b = blockIdx.x >> 5, q = blockIdx.x & 31;
  int t = threadIdx.x, lane = t & 63, w = t >> 6;
  __shared__ float sc[T_K];
  __shared__ float ps[T_K];
  int len = lens[b];
  float aqr[16], vh[16];
  const float* aqp = aq + (size_t)(b * T_Q + q) * HDIM + lane * 16;
  const float* vp  = vhat + lane * 16;
  #pragma unroll
  for (int j = 0; j < 4; j++){
    float4 v0 = ((const float4*)aqp)[j];
    float4 v1 = ((const float4*)vp)[j];
    aqr[j*4+0] = v0.x; aqr[j*4+1] = v0.y; aqr[j*4+2] = v0.z; aqr[j*4+3] = v0.w;
    vh[j*4+0]  = v1.x; vh[j*4+1]  = v1.y; vh[j*4+2]  = v1.z; vh[j*4+3]  = v1.w;
  }

  for (int kk = 0; kk < 12; kk++){
    int k = w * 12 + kk;
    const u16* akp = ak + (size_t)(k * NB + b) * HDIM + lane * 16;
    us8 a0 = *(const us8*)(akp);
    us8 a1 = *(const us8*)(akp + 8);
    float p = 0.f;
    #pragma unroll
    for (int j = 0; j < 8; j++){
      p += tanh_f(aqr[j]     + bf2f(a0[j])) * vh[j];
      p += tanh_f(aqr[8 + j] + bf2f(a1[j])) * vh[8 + j];
    }
    #pragma unroll
    for (int m = 32; m >= 1; m >>= 1) p += __shfl_xor(p, m);
    if (lane == 0) sc[k] = (k < len) ? p : MASK_FILL;
  }
  __syncthreads();
  float mx = -3.0e38f;
  #pragma unroll
  for (int k = 0; k < T_K; k++) mx = fmaxf(mx, sc[k]);
  if (t < T_K) ps[t] = (t < len) ? __expf(sc[t] - mx) : 0.f;
  __syncthreads();
  float den = 0.f;
  #pragma unroll
  for (int k = 0; k < T_K; k++) den += ps[k];
  float rden = __builtin_amdgcn_rcpf(den);

  float c0 = 0.f, c1 = 0.f, c2 = 0.f, c3 = 0.f;
  for (int k = 0; k < len; k++){
    float pk = ps[k];
    ushort4 kv = *(const ushort4*)(keys + (size_t)(k * NB + b) * HDIM + t * 4);
    c0 += pk * bf2f(kv.x); c1 += pk * bf2f(kv.y);
    c2 += pk * bf2f(kv.z); c3 += pk * bf2f(kv.w);
  }
  size_t o = (size_t)(q * NB + b) * HDIM + t * 4;
  out1[o + 0] = c0 * rden;
  out1[o + 1] = c1 * rden;
  out1[o + 2] = c2 * rden;
  out1[o + 3] = c3 * rden;
}

// ---------------- launch ----------------

extern "C" void kernel_launch(void* const* d_in, const int* in_sizes, int n_in,
                              void* d_out, int out_size, void* d_ws, size_t ws_size,
                              hipStream_t stream)
{
  const float* in1  = (const float*)d_in[0];   // input1
  const float* in0  = (const float*)d_in[1];   // input0
  const int*   lens = (const int*)d_in[2];     // input2
  const int*   toks = (const int*)d_in[3];     // input3
  const float* emb  = (const float*)d_in[4];
  const float* Wih  = (const float*)d_in[5];
  const float* Whh  = (const float*)d_in[6];
  const float* bih  = (const float*)d_in[7];
  const float* bhh  = (const float*)d_in[8];
  const float* Wq   = (const float*)d_in[9];
  const float* Wk   = (const float*)d_in[10];
  const float* vatt = (const float*)d_in[11];
  const float* ns   = (const float*)d_in[12];
  const float* nbb  = (const float*)d_in[13];

  char* p = (char*)d_ws;
  u16* x_bf    = (u16*)p;   p += (size_t)2048 * 1024 * 2;   // 4 MB
  u16* keys_bf = (u16*)p;   p += (size_t)3072 * 1024 * 2;   // 6 MB
  u16* hA      = (u16*)p;   p += (size_t)64 * 1024 * 2;
  u16* hB      = (u16*)p;   p += (size_t)64 * 1024 * 2;
  u16* qbuf    = (u16*)p;   p += (size_t)2048 * 1024 * 2;   // 4 MB
  u16* xp      = (u16*)p;   p += (size_t)2048 * 4096 * 2;   // 16 MB (dead after LSTM)
  float* vhat  = (float*)p; p += 1024 * 4;
  float* bsum  = (float*)p; p += 4096 * 4;
  float* nbf   = (float*)p; p += 1024 * 4;
  int* bar     = (int*)p;   p += 256;
  u16* ak      = (u16*)p;   p += (size_t)3072 * 1024 * 2;   // 6 MB
  u16* Wih_bf  = (u16*)p;   p += (size_t)4096 * 1024 * 2;   // 8 MB
  u16* Wq_bf   = (u16*)p;   p += (size_t)1024 * 1024 * 2;   // 2 MB
  u16* Wk_bf   = (u16*)p;   p += (size_t)1024 * 1024 * 2;   // 2 MB
  float* aq    = (float*)xp;   // 8 MB, aliases xp (xp fully consumed before aq GEMM)

  float* out0 = (float*)d_out;
  float* out1 = out0 + (size_t)T_Q * NB * HDIM;

  hipMemsetAsync(bar, 0, 256, stream);

  conv_f2b<<<4096, 256, 0, stream>>>(Wih, Wih_bf);
  conv_f2b<<<1024, 256, 0, stream>>>(Wq,  Wq_bf);
  conv_f2b<<<1024, 256, 0, stream>>>(Wk,  Wk_bf);
  gather_x<<<2048, 256, 0, stream>>>(toks, emb, x_bf);
  make_keys<<<3072, 256, 0, stream>>>(in1, in0, keys_bf);
  prep_small<<<1, 256, 0, stream>>>(vatt, ns, nbb, vhat, nbf);
  prep_bsum<<<16, 256, 0, stream>>>(bih, bhh, bsum);

  // xp = x * Wih^T + (bih + bhh) : M=2048, N=4096, K=1024 -> bf16
  gemm_bf16<1><<<dim3(64, 32), 256, 0, stream>>>(x_bf, Wih_bf, bsum, xp, 2048, 4096, 1024);
  // ak = keys * Wk^T + norm_bias : M=3072, N=1024, K=1024 -> bf16
  gemm_bf16<1><<<dim3(16, 48), 256, 0, stream>>>(keys_bf, Wk_bf, nbf, ak, 3072, 1024, 1024);

  // all 32 LSTM steps in one persistent kernel (144KB dynamic LDS, 1 block/CU)
  lstm_persistent<<<LSTM_BLOCKS, 512, 147456, stream>>>(Whh, xp, hA, hB, qbuf, out0, bar);

  // aq = q * Wq^T : M=2048, N=1024, K=1024 -> f32 (writes over xp region, now dead)
  gemm_bf16<0><<<dim3(16, 32), 256, 0, stream>>>(qbuf, Wq_bf, nullptr, aq, 2048, 1024, 1024);

  attn_fused<<<2048, 256, 0, stream>>>(aq, ak, vhat, keys_bf, lens, out1);
}

// Round 4
// 667.672 us; speedup vs baseline: 1.7659x; 1.2098x over previous
//
#include <hip/hip_runtime.h>
#include <hip/hip_bf16.h>

typedef unsigned short u16;
typedef __attribute__((ext_vector_type(8))) short bf16x8;
typedef __attribute__((ext_vector_type(8))) unsigned short us8;
typedef __attribute__((ext_vector_type(4))) float f32x4;

#define T_Q 32
#define T_K 48
#define NB 64
#define HDIM 1024
#define MASK_FILL -65504.0f
#define LSTM_BLOCKS 64

__device__ __forceinline__ float bf2f(u16 v){
  union { unsigned u; float f; } x; x.u = ((unsigned)v) << 16; return x.f;
}
__device__ __forceinline__ u16 f2bf(float f){
  union { float f; unsigned u; } x; x.f = f;
  return (u16)((x.u + 0x7FFFu + ((x.u >> 16) & 1u)) >> 16);
}
__device__ __forceinline__ float sigm(float x){
  return __builtin_amdgcn_rcpf(1.f + __expf(-x));
}
__device__ __forceinline__ float tanh_f(float x){
  float e = __expf(2.f * x);
  return fmaf(-2.f, __builtin_amdgcn_rcpf(e + 1.f), 1.f);  // graceful at +/-inf
}

// agent-scope (cross-XCD coherent) access: sc1 = write-through/read-around local L2,
// coherence point = Infinity Cache. No buffer_wbl2/inv needed.
__device__ __forceinline__ void st_b32_sc(u16* a, unsigned v){
  asm volatile("global_store_dword %0, %1, off sc1" :: "v"(a), "v"(v) : "memory");
}
__device__ __forceinline__ bf16x8 ld_b128_sc(const u16* a){
  bf16x8 r;
  asm volatile("global_load_dwordx4 %0, %1, off sc1" : "=v"(r) : "v"(a));
  return r;
}

#define MFMA16(A,B,C) __builtin_amdgcn_mfma_f32_16x16x32_bf16(A,B,C,0,0,0)

// ---------------- prep kernels ----------------

__global__ void conv_f2b(const float* __restrict__ s, u16* __restrict__ d){
  size_t i = ((size_t)blockIdx.x * 256 + threadIdx.x) * 4;
  float4 v = *(const float4*)(s + i);
  ushort4 o; o.x = f2bf(v.x); o.y = f2bf(v.y); o.z = f2bf(v.z); o.w = f2bf(v.w);
  *(ushort4*)(d + i) = o;
}

__global__ void gather_x(const int* __restrict__ tok, const float* __restrict__ emb,
                         u16* __restrict__ x){
  int r = blockIdx.x;                      // r = t*64 + b
  int token = tok[r];
  float4 v = ((const float4*)(emb + (size_t)token * HDIM))[threadIdx.x];
  ushort4 o; o.x = f2bf(v.x); o.y = f2bf(v.y); o.z = f2bf(v.z); o.w = f2bf(v.w);
  ((ushort4*)(x + (size_t)r * HDIM))[threadIdx.x] = o;
}

__global__ void make_keys(const float* __restrict__ a, const float* __restrict__ b,
                          u16* __restrict__ o){
  size_t i = ((size_t)blockIdx.x * 256 + threadIdx.x) * 4;
  float4 va = *(const float4*)(a + i);
  float4 vb = *(const float4*)(b + i);
  ushort4 vo;
  vo.x = f2bf(va.x + vb.x);
  vo.y = f2bf(va.y + vb.y);
  vo.z = f2bf(va.z + vb.z);
  vo.w = f2bf(va.w + vb.w);
  *(ushort4*)(o + i) = vo;
}

__global__ void prep_small(const float* __restrict__ vatt, const float* __restrict__ ns,
                           const float* __restrict__ nb,
                           float* __restrict__ vhat, float* __restrict__ nbias){
  __shared__ float wred[4];
  int t = threadIdx.x, lane = t & 63, w = t >> 6;
  float vv[4]; float s = 0.f;
  #pragma unroll
  for (int j = 0; j < 4; j++){ vv[j] = vatt[t*4 + j]; s += vv[j]*vv[j]; }
  #pragma unroll
  for (int m = 32; m >= 1; m >>= 1) s += __shfl_xor(s, m);
  if (lane == 0) wred[w] = s;
  __syncthreads();
  float tot = wred[0] + wred[1] + wred[2] + wred[3];
  float scale = ns[0] / sqrtf(tot);
  #pragma unroll
  for (int j = 0; j < 4; j++) vhat[t*4 + j] = vv[j] * scale;
  #pragma unroll
  for (int j = 0; j < 4; j++){ int i = t + 256*j; nbias[i] = nb[i]; }
}

__global__ void prep_bsum(const float* __restrict__ bih, const float* __restrict__ bhh,
                          float* __restrict__ bias_sum){
  int i = blockIdx.x * 256 + threadIdx.x;
  bias_sum[i] = bih[i] + bhh[i];
}

// ---------------- generic bf16 GEMM: C[M][N] = A[M][K] * W[N][K]^T + bias ----------------
// OB=1 -> bf16 output, OB=0 -> f32 output.

template<int OB>
__global__ __launch_bounds__(256) void gemm_bf16(
  const u16* __restrict__ A, const u16* __restrict__ W,
  const float* __restrict__ bias, void* __restrict__ Cv,
  int M, int N, int K)
{
  __shared__ __align__(16) u16 As[4][66][8];   // [kc][row][8], kc-stride 1056B
  __shared__ __align__(16) u16 Bs[4][66][8];
  const int t = threadIdx.x;
  const int m0 = blockIdx.y * 64, n0 = blockIdx.x * 64;
  const int lane = t & 63, w = t >> 6;
  const int wm = (w >> 1) * 32, wn = (w & 1) * 32;
  const int lr = lane & 15, g = lane >> 4;
  const int lrow = t >> 2, lkc = t & 3;
  f32x4 acc00 = {0,0,0,0}, acc01 = {0,0,0,0}, acc10 = {0,0,0,0}, acc11 = {0,0,0,0};
  const u16* aptr = A + (size_t)(m0 + lrow) * K + lkc * 8;
  const u16* wptr = W + (size_t)(n0 + lrow) * K + lkc * 8;
  for (int k0 = 0; k0 < K; k0 += 32){
    *(bf16x8*)(&As[lkc][lrow][0]) = *(const bf16x8*)(aptr + k0);
    *(bf16x8*)(&Bs[lkc][lrow][0]) = *(const bf16x8*)(wptr + k0);
    __syncthreads();
    bf16x8 a0 = *(const bf16x8*)(&As[g][wm      + lr][0]);
    bf16x8 a1 = *(const bf16x8*)(&As[g][wm + 16 + lr][0]);
    bf16x8 b0 = *(const bf16x8*)(&Bs[g][wn      + lr][0]);
    bf16x8 b1 = *(const bf16x8*)(&Bs[g][wn + 16 + lr][0]);
    acc00 = MFMA16(a0, b0, acc00);
    acc01 = MFMA16(a0, b1, acc01);
    acc10 = MFMA16(a1, b0, acc10);
    acc11 = MFMA16(a1, b1, acc11);
    __syncthreads();
  }
  // C/D layout: col = lane&15, row = (lane>>4)*4 + reg   [m89-verified]
  const int rb = m0 + wm + g * 4;
  const int cb = n0 + wn + lr;
  float bv0 = bias ? bias[cb]      : 0.f;
  float bv1 = bias ? bias[cb + 16] : 0.f;
  #pragma unroll
  for (int r = 0; r < 4; r++){
    float v00 = acc00[r] + bv0, v01 = acc01[r] + bv1;
    float v10 = acc10[r] + bv0, v11 = acc11[r] + bv1;
    if (OB){
      u16* C = (u16*)Cv;
      C[(size_t)(rb + r)      * N + cb]      = f2bf(v00);
      C[(size_t)(rb + r)      * N + cb + 16] = f2bf(v01);
      C[(size_t)(rb + 16 + r) * N + cb]      = f2bf(v10);
      C[(size_t)(rb + 16 + r) * N + cb + 16] = f2bf(v11);
    } else {
      float* C = (float*)Cv;
      C[(size_t)(rb + r)      * N + cb]      = v00;
      C[(size_t)(rb + r)      * N + cb + 16] = v01;
      C[(size_t)(rb + 16 + r) * N + cb]      = v10;
      C[(size_t)(rb + 16 + r) * N + cb + 16] = v11;
    }
  }
}

// ---------------- persistent LSTM ----------------
// 64 blocks x 512 threads. Block j owns h-cols [j*16, j*16+16) for all 4 gates.
// Whh slice (f32->bf16) resident in LDS across all 32 steps; c-state in registers.
// h exchanged via sc1 (L3-coherent) loads/stores; barrier = atomicAdd + relaxed spin.
// NO cache-flush fences. A-frags pipelined 6 pairs deep w/ counted vmcnt waits.

__global__ __launch_bounds__(512, 1) void lstm_persistent(
  const float* __restrict__ Whh, const u16* __restrict__ xp,
  u16* __restrict__ hA, u16* __restrict__ hB,
  u16* __restrict__ qbuf, float* __restrict__ out0,
  int* __restrict__ bar)
{
  extern __shared__ char smem[];
  u16*  wlds = (u16*)smem;                    // [4][32][16][32] bf16
  float* gl  = (float*)(smem + 131072);       // [4][64][16] f32

  const int tid = threadIdx.x;
  const int c0 = blockIdx.x * 16;
  const int lane = tid & 63, w = tid >> 6;    // 8 waves
  const int gate = w & 3, msub = w >> 2;      // wave -> (gate, m-half)
  const int lr = lane & 15, g = lane >> 4;

  // ---- one-time: Whh slice f32 -> bf16 -> LDS ----
  #pragma unroll
  for (int i = 0; i < 16; i++){
    int e = (i * 512 + tid) * 8;               // element in 64x1024 slice
    int R = e >> 10, k = e & 1023;
    int gg = R >> 4, rr = R & 15, tt = k >> 5, kk = k & 31;
    const float* src = Whh + (size_t)((gg << 10) + c0 + rr) * 1024 + k;
    float4 v0 = *(const float4*)(src);
    float4 v1 = *(const float4*)(src + 4);
    u16* dst = wlds + (((gg * 32 + tt) * 16 + rr) * 32 + kk);
    ushort4 o0, o1;
    o0.x = f2bf(v0.x); o0.y = f2bf(v0.y); o0.z = f2bf(v0.z); o0.w = f2bf(v0.w);
    o1.x = f2bf(v1.x); o1.y = f2bf(v1.y); o1.z = f2bf(v1.z); o1.w = f2bf(v1.w);
    *(ushort4*)dst = o0; *(ushort4*)(dst + 4) = o1;
  }
  __syncthreads();

  // pointwise ownership: 2 cells/thread
  const int pb = (tid * 2) >> 4;               // batch 0..63
  const int pc = (tid * 2) & 15;               // col pair base (even)
  float c_state0 = 0.f, c_state1 = 0.f;

  const int arow = msub * 32 + lr;             // batch rows for this wave's m-tiles

  #pragma unroll 1
  for (int step = 0; step < T_Q; step++){
    const u16* hprev = (step & 1) ? hB : hA;
    u16* hnext       = (step & 1) ? hA : hB;
    f32x4 acc0 = {0,0,0,0}, acc1 = {0,0,0,0};

    if (step > 0){
      const u16* base0 = hprev + (size_t)arow * HDIM + g * 8;
      const u16* base1 = base0 + 16 * HDIM;
      bf16x8 a0[6], a1[6];
      #pragma unroll
      for (int p = 0; p < 6; p++){
        a0[p] = ld_b128_sc(base0 + p * 32);
        a1[p] = ld_b128_sc(base1 + p * 32);
      }
      bf16x8 bfr[2];
      bfr[0] = *(const bf16x8*)(wlds + ((size_t)(gate * 32 + 0) * 16 + lr) * 32 + g * 8);
      bfr[1] = *(const bf16x8*)(wlds + ((size_t)(gate * 32 + 1) * 16 + lr) * 32 + g * 8);

#define LSTM_ITER(T, WN) \
      do { \
        asm volatile("s_waitcnt vmcnt(" #WN ")" ::: "memory"); \
        __builtin_amdgcn_sched_barrier(0); \
        acc0 = MFMA16(a0[(T) % 6], bfr[(T) & 1], acc0); \
        acc1 = MFMA16(a1[(T) % 6], bfr[(T) & 1], acc1); \
        if ((T) < 30) \
          bfr[(T) & 1] = *(const bf16x8*)(wlds + ((size_t)(gate * 32 + (T) + 2) * 16 + lr) * 32 + g * 8); \
        if ((T) < 26){ \
          a0[(T) % 6] = ld_b128_sc(base0 + ((T) + 6) * 32); \
          a1[(T) % 6] = ld_b128_sc(base1 + ((T) + 6) * 32); \
        } \
      } while (0)

      LSTM_ITER(0,10);  LSTM_ITER(1,10);  LSTM_ITER(2,10);  LSTM_ITER(3,10);
      LSTM_ITER(4,10);  LSTM_ITER(5,10);  LSTM_ITER(6,10);  LSTM_ITER(7,10);
      LSTM_ITER(8,10);  LSTM_ITER(9,10);  LSTM_ITER(10,10); LSTM_ITER(11,10);
      LSTM_ITER(12,10); LSTM_ITER(13,10); LSTM_ITER(14,10); LSTM_ITER(15,10);
      LSTM_ITER(16,10); LSTM_ITER(17,10); LSTM_ITER(18,10); LSTM_ITER(19,10);
      LSTM_ITER(20,10); LSTM_ITER(21,10); LSTM_ITER(22,10); LSTM_ITER(23,10);
      LSTM_ITER(24,10); LSTM_ITER(25,10); LSTM_ITER(26,10); LSTM_ITER(27,8);
      LSTM_ITER(28,6);  LSTM_ITER(29,4);  LSTM_ITER(30,2);  LSTM_ITER(31,0);
#undef LSTM_ITER
    }

    // gate preacts -> LDS exchange. C/D: col=lane&15, row=(lane>>4)*4+reg
    #pragma unroll
    for (int r = 0; r < 4; r++){
      gl[(gate * 64 + msub * 32 +      g * 4 + r) * 16 + lr] = acc0[r];
      gl[(gate * 64 + msub * 32 + 16 + g * 4 + r) * 16 + lr] = acc1[r];
    }
    __syncthreads();

    // pointwise: 2 cells (pb, pc) (pb, pc+1)
    const u16* xr = xp + ((size_t)(step * NB + pb)) * 4096 + c0 + pc;
    float hout0, hout1; u16 hb0, hb1;
    {
      float ig = gl[(0 * 64 + pb) * 16 + pc] + bf2f(xr[0]);
      float fg = gl[(1 * 64 + pb) * 16 + pc] + bf2f(xr[1024]);
      float gg = gl[(2 * 64 + pb) * 16 + pc] + bf2f(xr[2048]);
      float og = gl[(3 * 64 + pb) * 16 + pc] + bf2f(xr[3072]);
      float cn = sigm(fg) * c_state0 + sigm(ig) * tanh_f(gg);
      c_state0 = cn;
      hout0 = sigm(og) * tanh_f(cn); hb0 = f2bf(hout0);
    }
    {
      float ig = gl[(0 * 64 + pb) * 16 + pc + 1] + bf2f(xr[1]);
      float fg = gl[(1 * 64 + pb) * 16 + pc + 1] + bf2f(xr[1025]);
      float gg = gl[(2 * 64 + pb) * 16 + pc + 1] + bf2f(xr[2049]);
      float og = gl[(3 * 64 + pb) * 16 + pc + 1] + bf2f(xr[3073]);
      float cn = sigm(fg) * c_state1 + sigm(ig) * tanh_f(gg);
      c_state1 = cn;
      hout1 = sigm(og) * tanh_f(cn); hb1 = f2bf(hout1);
    }
    // h -> coherent point (L3) via sc1; qbuf/out0 via normal path (read after kernel end)
    unsigned hpack = (unsigned)hb0 | ((unsigned)hb1 << 16);
    st_b32_sc(hnext + (size_t)pb * HDIM + c0 + pc, hpack);
    ushort2 hh; hh.x = hb0; hh.y = hb1;
    *(ushort2*)(qbuf + ((size_t)pb * T_Q + step) * HDIM + c0 + pc) = hh;
    float2 ho; ho.x = hout0; ho.y = hout1;
    *(float2*)(out0 + ((size_t)(step * NB + pb)) * HDIM + c0 + pc) = ho;

    // ---- grid barrier: no cache flushes. vmcnt(0) => sc1 stores are at L3. ----
    asm volatile("s_waitcnt vmcnt(0)" ::: "memory");
    __syncthreads();
    if (tid == 0){
      __hip_atomic_fetch_add(bar, 1, __ATOMIC_RELAXED, __HIP_MEMORY_SCOPE_AGENT);
      const int target = LSTM_BLOCKS * (step + 1);
      while (__hip_atomic_load(bar, __ATOMIC_RELAXED, __HIP_MEMORY_SCOPE_AGENT) < target)
        __builtin_amdgcn_s_sleep(1);
    }
    __syncthreads();
  }
}

// ---------------- fused attention: scores -> softmax -> context ----------------
// block per (b,q). wave w handles keys k in [w*12, min(len,w*12+12)). len-bounded:
// masked keys contribute exactly 0 to softmax/context, so skip their tanh work.

__global__ __launch_bounds__(256) void attn_fused(
  const float* __restrict__ aq, const u16* __restrict__ ak,
  const float* __restrict__ vhat, const u16* __restrict__ keys,
  const int* __restrict__ lens, float* __restrict__ out1)
{
  int b = blockIdx.x >> 5, q = blockIdx.x & 31;
  int t = threadIdx.x, lane = t & 63, w = t >> 6;
  __shared__ float sc[T_K];
  __shared__ float ps[T_K];
  int len = lens[b];
  float aqr[16], vh[16];
  const float* aqp = aq + (size_t)(b * T_Q + q) * HDIM + lane * 16;
  const float* vp  = vhat + lane * 16;
  #pragma unroll
  for (int j = 0; j < 4; j++){
    float4 v0 = ((const float4*)aqp)[j];
    float4 v1 = ((const float4*)vp)[j];
    aqr[j*4+0] = v0.x; aqr[j*4+1] = v0.y; aqr[j*4+2] = v0.z; aqr[j*4+3] = v0.w;
    vh[j*4+0]  = v1.x; vh[j*4+1]  = v1.y; vh[j*4+2]  = v1.z; vh[j*4+3]  = v1.w;
  }

  int kmax = len - w * 12; if (kmax > 12) kmax = 12;
  for (int kk = 0; kk < kmax; kk++){
    int k = w * 12 + kk;
    const u16* akp = ak + (size_t)(k * NB + b) * HDIM + lane * 16;
    us8 a0 = *(const us8*)(akp);
    us8 a1 = *(const us8*)(akp + 8);
    float p = 0.f;
    #pragma unroll
    for (int j = 0; j < 8; j++){
      p += tanh_f(aqr[j]     + bf2f(a0[j])) * vh[j];
      p += tanh_f(aqr[8 + j] + bf2f(a1[j])) * vh[8 + j];
    }
    #pragma unroll
    for (int m = 32; m >= 1; m >>= 1) p += __shfl_xor(p, m);
    if (lane == 0) sc[k] = p;
  }
  __syncthreads();
  float mx = -3.0e38f;
  for (int k = 0; k < len; k++) mx = fmaxf(mx, sc[k]);
  if (t < len) ps[t] = __expf(sc[t] - mx);
  __syncthreads();
  float den = 0.f;
  for (int k = 0; k < len; k++) den += ps[k];
  float rden = __builtin_amdgcn_rcpf(den);

  float c0 = 0.f, c1 = 0.f, c2 = 0.f, c3 = 0.f;
  for (int k = 0; k < len; k++){
    float pk = ps[k];
    ushort4 kv = *(const ushort4*)(keys + (size_t)(k * NB + b) * HDIM + t * 4);
    c0 += pk * bf2f(kv.x); c1 += pk * bf2f(kv.y);
    c2 += pk * bf2f(kv.z); c3 += pk * bf2f(kv.w);
  }
  size_t o = (size_t)(q * NB + b) * HDIM + t * 4;
  out1[o + 0] = c0 * rden;
  out1[o + 1] = c1 * rden;
  out1[o + 2] = c2 * rden;
  out1[o + 3] = c3 * rden;
}

// ---------------- launch ----------------

extern "C" void kernel_launch(void* const* d_in, const int* in_sizes, int n_in,
                              void* d_out, int out_size, void* d_ws, size_t ws_size,
                              hipStream_t stream)
{
  const float* in1  = (const float*)d_in[0];   // input1
  const float* in0  = (const float*)d_in[1];   // input0
  const int*   lens = (const int*)d_in[2];     // input2
  const int*   toks = (const int*)d_in[3];     // input3
  const float* emb  = (const float*)d_in[4];
  const float* Wih  = (const float*)d_in[5];
  const float* Whh  = (const float*)d_in[6];
  const float* bih  = (const float*)d_in[7];
  const float* bhh  = (const float*)d_in[8];
  const float* Wq   = (const float*)d_in[9];
  const float* Wk   = (const float*)d_in[10];
  const float* vatt = (const float*)d_in[11];
  const float* ns   = (const float*)d_in[12];
  const float* nbb  = (const float*)d_in[13];

  char* p = (char*)d_ws;
  u16* x_bf    = (u16*)p;   p += (size_t)2048 * 1024 * 2;   // 4 MB
  u16* keys_bf = (u16*)p;   p += (size_t)3072 * 1024 * 2;   // 6 MB
  u16* hA      = (u16*)p;   p += (size_t)64 * 1024 * 2;
  u16* hB      = (u16*)p;   p += (size_t)64 * 1024 * 2;
  u16* qbuf    = (u16*)p;   p += (size_t)2048 * 1024 * 2;   // 4 MB
  u16* xp      = (u16*)p;   p += (size_t)2048 * 4096 * 2;   // 16 MB (dead after LSTM)
  float* vhat  = (float*)p; p += 1024 * 4;
  float* bsum  = (float*)p; p += 4096 * 4;
  float* nbf   = (float*)p; p += 1024 * 4;
  int* bar     = (int*)p;   p += 256;
  u16* ak      = (u16*)p;   p += (size_t)3072 * 1024 * 2;   // 6 MB
  u16* Wih_bf  = (u16*)p;   p += (size_t)4096 * 1024 * 2;   // 8 MB
  u16* Wq_bf   = (u16*)p;   p += (size_t)1024 * 1024 * 2;   // 2 MB
  u16* Wk_bf   = (u16*)p;   p += (size_t)1024 * 1024 * 2;   // 2 MB
  float* aq    = (float*)xp;   // 8 MB, aliases xp (xp fully consumed before aq GEMM)

  float* out0 = (float*)d_out;
  float* out1 = out0 + (size_t)T_Q * NB * HDIM;

  hipMemsetAsync(bar, 0, 256, stream);

  conv_f2b<<<4096, 256, 0, stream>>>(Wih, Wih_bf);
  conv_f2b<<<1024, 256, 0, stream>>>(Wq,  Wq_bf);
  conv_f2b<<<1024, 256, 0, stream>>>(Wk,  Wk_bf);
  gather_x<<<2048, 256, 0, stream>>>(toks, emb, x_bf);
  make_keys<<<3072, 256, 0, stream>>>(in1, in0, keys_bf);
  prep_small<<<1, 256, 0, stream>>>(vatt, ns, nbb, vhat, nbf);
  prep_bsum<<<16, 256, 0, stream>>>(bih, bhh, bsum);

  // xp = x * Wih^T + (bih + bhh) : M=2048, N=4096, K=1024 -> bf16
  gemm_bf16<1><<<dim3(64, 32), 256, 0, stream>>>(x_bf, Wih_bf, bsum, xp, 2048, 4096, 1024);
  // ak = keys * Wk^T + norm_bias : M=3072, N=1024, K=1024 -> bf16
  gemm_bf16<1><<<dim3(16, 48), 256, 0, stream>>>(keys_bf, Wk_bf, nbf, ak, 3072, 1024, 1024);

  // all 32 LSTM steps in one persistent kernel (144KB dynamic LDS, 1 block/CU)
  lstm_persistent<<<LSTM_BLOCKS, 512, 147456, stream>>>(Whh, xp, hA, hB, qbuf, out0, bar);

  // aq = q * Wq^T : M=2048, N=1024, K=1024 -> f32 (writes over xp region, now dead)
  gemm_bf16<0><<<dim3(16, 32), 256, 0, stream>>>(qbuf, Wq_bf, nullptr, aq, 2048, 1024, 1024);

  attn_fused<<<2048, 256, 0, stream>>>(aq, ak, vhat, keys_bf, lens, out1);
}

// Round 5
// 641.896 us; speedup vs baseline: 1.8369x; 1.0402x over previous
//
#include <hip/hip_runtime.h>
#include <hip/hip_bf16.h>

typedef unsigned short u16;
typedef __attribute__((ext_vector_type(8))) short bf16x8;
typedef __attribute__((ext_vector_type(8))) unsigned short us8;
typedef __attribute__((ext_vector_type(4))) float f32x4;

#define T_Q 32
#define T_K 48
#define NB 64
#define HDIM 1024
#define MASK_FILL -65504.0f
#define LSTM_BLOCKS 64

__device__ __forceinline__ float bf2f(u16 v){
  union { unsigned u; float f; } x; x.u = ((unsigned)v) << 16; return x.f;
}
__device__ __forceinline__ u16 f2bf(float f){
  union { float f; unsigned u; } x; x.f = f;
  return (u16)((x.u + 0x7FFFu + ((x.u >> 16) & 1u)) >> 16);
}
__device__ __forceinline__ float sigm(float x){
  return __builtin_amdgcn_rcpf(1.f + __expf(-x));
}
__device__ __forceinline__ float tanh_f(float x){
  float e = __expf(2.f * x);
  return fmaf(-2.f, __builtin_amdgcn_rcpf(e + 1.f), 1.f);  // graceful at +/-inf
}

// Cross-XCD coherent accesses: sc0 (bypass L0/L1) + sc1 (bypass non-coherent L2).
// Coherence point = Infinity Cache. All sync-path accesses are explicit asm --
// r3/r4 lesson: the intrinsic-lowered spin load was served stale (barrier
// resolved by cache eviction, ~15us/step).
__device__ __forceinline__ void st_b32_cc(u16* a, unsigned v){
  asm volatile("global_store_dword %0, %1, off sc0 sc1" :: "v"(a), "v"(v) : "memory");
}
__device__ __forceinline__ void st_flag(int* a, int v){
  asm volatile("global_store_dword %0, %1, off sc0 sc1" :: "v"(a), "v"(v) : "memory");
}
__device__ __forceinline__ int ld_flag(const int* a){
  int r;
  asm volatile("global_load_dword %0, %1, off sc0 sc1\n\ts_waitcnt vmcnt(0)"
               : "=v"(r) : "v"(a) : "memory");
  return r;
}
__device__ __forceinline__ bf16x8 ld_b128_cc(const u16* a){
  bf16x8 r;
  asm volatile("global_load_dwordx4 %0, %1, off sc0 sc1" : "=v"(r) : "v"(a));
  return r;
}

#define MFMA16(A,B,C) __builtin_amdgcn_mfma_f32_16x16x32_bf16(A,B,C,0,0,0)

// ---------------- prep kernels ----------------

__global__ void conv_f2b(const float* __restrict__ s, u16* __restrict__ d){
  size_t i = ((size_t)blockIdx.x * 256 + threadIdx.x) * 4;
  float4 v = *(const float4*)(s + i);
  ushort4 o; o.x = f2bf(v.x); o.y = f2bf(v.y); o.z = f2bf(v.z); o.w = f2bf(v.w);
  *(ushort4*)(d + i) = o;
}

__global__ void gather_x(const int* __restrict__ tok, const float* __restrict__ emb,
                         u16* __restrict__ x){
  int r = blockIdx.x;                      // r = t*64 + b
  int token = tok[r];
  float4 v = ((const float4*)(emb + (size_t)token * HDIM))[threadIdx.x];
  ushort4 o; o.x = f2bf(v.x); o.y = f2bf(v.y); o.z = f2bf(v.z); o.w = f2bf(v.w);
  ((ushort4*)(x + (size_t)r * HDIM))[threadIdx.x] = o;
}

__global__ void make_keys(const float* __restrict__ a, const float* __restrict__ b,
                          u16* __restrict__ o){
  size_t i = ((size_t)blockIdx.x * 256 + threadIdx.x) * 4;
  float4 va = *(const float4*)(a + i);
  float4 vb = *(const float4*)(b + i);
  ushort4 vo;
  vo.x = f2bf(va.x + vb.x);
  vo.y = f2bf(va.y + vb.y);
  vo.z = f2bf(va.z + vb.z);
  vo.w = f2bf(va.w + vb.w);
  *(ushort4*)(o + i) = vo;
}

__global__ void prep_small(const float* __restrict__ vatt, const float* __restrict__ ns,
                           const float* __restrict__ nb,
                           float* __restrict__ vhat, float* __restrict__ nbias){
  __shared__ float wred[4];
  int t = threadIdx.x, lane = t & 63, w = t >> 6;
  float vv[4]; float s = 0.f;
  #pragma unroll
  for (int j = 0; j < 4; j++){ vv[j] = vatt[t*4 + j]; s += vv[j]*vv[j]; }
  #pragma unroll
  for (int m = 32; m >= 1; m >>= 1) s += __shfl_xor(s, m);
  if (lane == 0) wred[w] = s;
  __syncthreads();
  float tot = wred[0] + wred[1] + wred[2] + wred[3];
  float scale = ns[0] / sqrtf(tot);
  #pragma unroll
  for (int j = 0; j < 4; j++) vhat[t*4 + j] = vv[j] * scale;
  #pragma unroll
  for (int j = 0; j < 4; j++){ int i = t + 256*j; nbias[i] = nb[i]; }
}

__global__ void prep_bsum(const float* __restrict__ bih, const float* __restrict__ bhh,
                          float* __restrict__ bias_sum){
  int i = blockIdx.x * 256 + threadIdx.x;
  bias_sum[i] = bih[i] + bhh[i];
}

// ---------------- generic bf16 GEMM: C[M][N] = A[M][K] * W[N][K]^T + bias ----------------
// OB=1 -> bf16 output, OB=0 -> f32 output.

template<int OB>
__global__ __launch_bounds__(256) void gemm_bf16(
  const u16* __restrict__ A, const u16* __restrict__ W,
  const float* __restrict__ bias, void* __restrict__ Cv,
  int M, int N, int K)
{
  __shared__ __align__(16) u16 As[4][66][8];   // [kc][row][8], kc-stride 1056B
  __shared__ __align__(16) u16 Bs[4][66][8];
  const int t = threadIdx.x;
  const int m0 = blockIdx.y * 64, n0 = blockIdx.x * 64;
  const int lane = t & 63, w = t >> 6;
  const int wm = (w >> 1) * 32, wn = (w & 1) * 32;
  const int lr = lane & 15, g = lane >> 4;
  const int lrow = t >> 2, lkc = t & 3;
  f32x4 acc00 = {0,0,0,0}, acc01 = {0,0,0,0}, acc10 = {0,0,0,0}, acc11 = {0,0,0,0};
  const u16* aptr = A + (size_t)(m0 + lrow) * K + lkc * 8;
  const u16* wptr = W + (size_t)(n0 + lrow) * K + lkc * 8;
  for (int k0 = 0; k0 < K; k0 += 32){
    *(bf16x8*)(&As[lkc][lrow][0]) = *(const bf16x8*)(aptr + k0);
    *(bf16x8*)(&Bs[lkc][lrow][0]) = *(const bf16x8*)(wptr + k0);
    __syncthreads();
    bf16x8 a0 = *(const bf16x8*)(&As[g][wm      + lr][0]);
    bf16x8 a1 = *(const bf16x8*)(&As[g][wm + 16 + lr][0]);
    bf16x8 b0 = *(const bf16x8*)(&Bs[g][wn      + lr][0]);
    bf16x8 b1 = *(const bf16x8*)(&Bs[g][wn + 16 + lr][0]);
    acc00 = MFMA16(a0, b0, acc00);
    acc01 = MFMA16(a0, b1, acc01);
    acc10 = MFMA16(a1, b0, acc10);
    acc11 = MFMA16(a1, b1, acc11);
    __syncthreads();
  }
  // C/D layout: col = lane&15, row = (lane>>4)*4 + reg   [m89-verified]
  const int rb = m0 + wm + g * 4;
  const int cb = n0 + wn + lr;
  float bv0 = bias ? bias[cb]      : 0.f;
  float bv1 = bias ? bias[cb + 16] : 0.f;
  #pragma unroll
  for (int r = 0; r < 4; r++){
    float v00 = acc00[r] + bv0, v01 = acc01[r] + bv1;
    float v10 = acc10[r] + bv0, v11 = acc11[r] + bv1;
    if (OB){
      u16* C = (u16*)Cv;
      C[(size_t)(rb + r)      * N + cb]      = f2bf(v00);
      C[(size_t)(rb + r)      * N + cb + 16] = f2bf(v01);
      C[(size_t)(rb + 16 + r) * N + cb]      = f2bf(v10);
      C[(size_t)(rb + 16 + r) * N + cb + 16] = f2bf(v11);
    } else {
      float* C = (float*)Cv;
      C[(size_t)(rb + r)      * N + cb]      = v00;
      C[(size_t)(rb + r)      * N + cb + 16] = v01;
      C[(size_t)(rb + 16 + r) * N + cb]      = v10;
      C[(size_t)(rb + 16 + r) * N + cb + 16] = v11;
    }
  }
}

// ---------------- persistent LSTM ----------------
// 64 blocks x 512 threads. Block j owns h-cols [j*16, j*16+16) for all 4 gates.
// Whh slice (f32->bf16) resident in LDS across all 32 steps; c-state in registers.
// Sync: single-writer flag per block (sc0 sc1 asm store), wave-0 64-lane poll
// (sc0 sc1 asm loads + ballot) -- one L3 round trip, no atomics, no eviction
// dependence. h exchanged via sc0 sc1 loads/stores; A-frags 8-deep rolling
// pipeline with counted vmcnt + sched_barrier(0).

__global__ __launch_bounds__(512, 1) void lstm_persistent(
  const float* __restrict__ Whh, const u16* __restrict__ xp,
  u16* __restrict__ hA, u16* __restrict__ hB,
  u16* __restrict__ qbuf, float* __restrict__ out0,
  int* __restrict__ flags)
{
  extern __shared__ char smem[];
  u16*  wlds = (u16*)smem;                    // [4][32][16][32] bf16
  float* gl  = (float*)(smem + 131072);       // [4][64][16] f32

  const int tid = threadIdx.x;
  const int c0 = blockIdx.x * 16;
  const int lane = tid & 63, w = tid >> 6;    // 8 waves
  const int gate = w & 3, msub = w >> 2;      // wave -> (gate, m-half)
  const int lr = lane & 15, g = lane >> 4;

  // ---- one-time: Whh slice f32 -> bf16 -> LDS ----
  #pragma unroll
  for (int i = 0; i < 16; i++){
    int e = (i * 512 + tid) * 8;               // element in 64x1024 slice
    int R = e >> 10, k = e & 1023;
    int gg = R >> 4, rr = R & 15, tt = k >> 5, kk = k & 31;
    const float* src = Whh + (size_t)((gg << 10) + c0 + rr) * 1024 + k;
    float4 v0 = *(const float4*)(src);
    float4 v1 = *(const float4*)(src + 4);
    u16* dst = wlds + (((gg * 32 + tt) * 16 + rr) * 32 + kk);
    ushort4 o0, o1;
    o0.x = f2bf(v0.x); o0.y = f2bf(v0.y); o0.z = f2bf(v0.z); o0.w = f2bf(v0.w);
    o1.x = f2bf(v1.x); o1.y = f2bf(v1.y); o1.z = f2bf(v1.z); o1.w = f2bf(v1.w);
    *(ushort4*)dst = o0; *(ushort4*)(dst + 4) = o1;
  }
  __syncthreads();

  // pointwise ownership: 2 cells/thread
  const int pb = (tid * 2) >> 4;               // batch 0..63
  const int pc = (tid * 2) & 15;               // col pair base (even)
  float c_state0 = 0.f, c_state1 = 0.f;

  const int arow = msub * 32 + lr;             // batch rows for this wave's m-tiles

  #pragma unroll 1
  for (int step = 0; step < T_Q; step++){
    const u16* hprev = (step & 1) ? hB : hA;
    u16* hnext       = (step & 1) ? hA : hB;
    f32x4 acc0 = {0,0,0,0}, acc1 = {0,0,0,0};

    if (step > 0){
      // ---- gate: wait until all blocks published h for this step ----
      if (w == 0){
        const int* fp = flags + lane * 16;
        for (;;){
          int f = ld_flag(fp);
          if (__ballot(f >= step) == ~0ull) break;
          __builtin_amdgcn_s_sleep(1);
        }
      }
      __syncthreads();

      const u16* base0 = hprev + (size_t)arow * HDIM + g * 8;
      const u16* base1 = base0 + 16 * HDIM;
      bf16x8 a0[8], a1[8];
      #pragma unroll
      for (int p = 0; p < 8; p++){
        a0[p] = ld_b128_cc(base0 + p * 32);
        a1[p] = ld_b128_cc(base1 + p * 32);
      }
      bf16x8 bfr[2];
      bfr[0] = *(const bf16x8*)(wlds + ((size_t)(gate * 32 + 0) * 16 + lr) * 32 + g * 8);
      bfr[1] = *(const bf16x8*)(wlds + ((size_t)(gate * 32 + 1) * 16 + lr) * 32 + g * 8);

#define LSTM_ITER(T, WN) \
      do { \
        asm volatile("s_waitcnt vmcnt(" #WN ")" ::: "memory"); \
        __builtin_amdgcn_sched_barrier(0); \
        acc0 = MFMA16(a0[(T) & 7], bfr[(T) & 1], acc0); \
        acc1 = MFMA16(a1[(T) & 7], bfr[(T) & 1], acc1); \
        if ((T) < 30) \
          bfr[(T) & 1] = *(const bf16x8*)(wlds + ((size_t)(gate * 32 + (T) + 2) * 16 + lr) * 32 + g * 8); \
        if ((T) < 24){ \
          a0[(T) & 7] = ld_b128_cc(base0 + ((T) + 8) * 32); \
          a1[(T) & 7] = ld_b128_cc(base1 + ((T) + 8) * 32); \
        } \
      } while (0)

      LSTM_ITER(0,14);  LSTM_ITER(1,14);  LSTM_ITER(2,14);  LSTM_ITER(3,14);
      LSTM_ITER(4,14);  LSTM_ITER(5,14);  LSTM_ITER(6,14);  LSTM_ITER(7,14);
      LSTM_ITER(8,14);  LSTM_ITER(9,14);  LSTM_ITER(10,14); LSTM_ITER(11,14);
      LSTM_ITER(12,14); LSTM_ITER(13,14); LSTM_ITER(14,14); LSTM_ITER(15,14);
      LSTM_ITER(16,14); LSTM_ITER(17,14); LSTM_ITER(18,14); LSTM_ITER(19,14);
      LSTM_ITER(20,14); LSTM_ITER(21,14); LSTM_ITER(22,14); LSTM_ITER(23,14);
      LSTM_ITER(24,14); LSTM_ITER(25,12); LSTM_ITER(26,10); LSTM_ITER(27,8);
      LSTM_ITER(28,6);  LSTM_ITER(29,4);  LSTM_ITER(30,2);  LSTM_ITER(31,0);
#undef LSTM_ITER
    }

    // prefetch this step's xp slice for the pointwise (normal loads; issued
    // after all asm loads drained so vmcnt bookkeeping stays exact)
    const u16* xr = xp + ((size_t)(step * NB + pb)) * 4096 + c0 + pc;
    unsigned xw0 = *(const unsigned*)(xr);
    unsigned xw1 = *(const unsigned*)(xr + 1024);
    unsigned xw2 = *(const unsigned*)(xr + 2048);
    unsigned xw3 = *(const unsigned*)(xr + 3072);

    // gate preacts -> LDS exchange. C/D: col=lane&15, row=(lane>>4)*4+reg
    #pragma unroll
    for (int r = 0; r < 4; r++){
      gl[(gate * 64 + msub * 32 +      g * 4 + r) * 16 + lr] = acc0[r];
      gl[(gate * 64 + msub * 32 + 16 + g * 4 + r) * 16 + lr] = acc1[r];
    }
    __syncthreads();

    // pointwise: 2 cells (pb, pc) (pb, pc+1)
    float hout0, hout1; u16 hb0, hb1;
    {
      float ig = gl[(0 * 64 + pb) * 16 + pc] + bf2f((u16)(xw0 & 0xFFFF));
      float fg = gl[(1 * 64 + pb) * 16 + pc] + bf2f((u16)(xw1 & 0xFFFF));
      float gg = gl[(2 * 64 + pb) * 16 + pc] + bf2f((u16)(xw2 & 0xFFFF));
      float og = gl[(3 * 64 + pb) * 16 + pc] + bf2f((u16)(xw3 & 0xFFFF));
      float cn = sigm(fg) * c_state0 + sigm(ig) * tanh_f(gg);
      c_state0 = cn;
      hout0 = sigm(og) * tanh_f(cn); hb0 = f2bf(hout0);
    }
    {
      float ig = gl[(0 * 64 + pb) * 16 + pc + 1] + bf2f((u16)(xw0 >> 16));
      float fg = gl[(1 * 64 + pb) * 16 + pc + 1] + bf2f((u16)(xw1 >> 16));
      float gg = gl[(2 * 64 + pb) * 16 + pc + 1] + bf2f((u16)(xw2 >> 16));
      float og = gl[(3 * 64 + pb) * 16 + pc + 1] + bf2f((u16)(xw3 >> 16));
      float cn = sigm(fg) * c_state1 + sigm(ig) * tanh_f(gg);
      c_state1 = cn;
      hout1 = sigm(og) * tanh_f(cn); hb1 = f2bf(hout1);
    }

    if (step < T_Q - 1){
      // critical path: h slice -> L3, then flag. qbuf/out0 deferred below.
      unsigned hpack = (unsigned)hb0 | ((unsigned)hb1 << 16);
      st_b32_cc(hnext + (size_t)pb * HDIM + c0 + pc, hpack);
      asm volatile("s_waitcnt vmcnt(0)" ::: "memory");
      __syncthreads();                          // whole block's h is at L3
      if (tid == 0) st_flag(flags + blockIdx.x * 16, step + 1);
    }

    ushort2 hh; hh.x = hb0; hh.y = hb1;
    *(ushort2*)(qbuf + ((size_t)pb * T_Q + step) * HDIM + c0 + pc) = hh;
    float2 ho; ho.x = hout0; ho.y = hout1;
    *(float2*)(out0 + ((size_t)(step * NB + pb)) * HDIM + c0 + pc) = ho;
  }
}

// ---------------- fused attention: scores -> softmax -> context ----------------
// block per (b,q). wave w handles keys k in [w*12, min(len,w*12+12)). len-bounded:
// masked keys contribute exactly 0 to softmax/context, so skip their tanh work.

__global__ __launch_bounds__(256) void attn_fused(
  const float* __restrict__ aq, const u16* __restrict__ ak,
  const float* __restrict__ vhat, const u16* __restrict__ keys,
  const int* __restrict__ lens, float* __restrict__ out1)
{
  int b = blockIdx.x >> 5, q = blockIdx.x & 31;
  int t = threadIdx.x, lane = t & 63, w = t >> 6;
  __shared__ float sc[T_K];
  __shared__ float ps[T_K];
  int len = lens[b];
  float aqr[16], vh[16];
  const float* aqp = aq + (size_t)(b * T_Q + q) * HDIM + lane * 16;
  const float* vp  = vhat + lane * 16;
  #pragma unroll
  for (int j = 0; j < 4; j++){
    float4 v0 = ((const float4*)aqp)[j];
    float4 v1 = ((const float4*)vp)[j];
    aqr[j*4+0] = v0.x; aqr[j*4+1] = v0.y; aqr[j*4+2] = v0.z; aqr[j*4+3] = v0.w;
    vh[j*4+0]  = v1.x; vh[j*4+1]  = v1.y; vh[j*4+2]  = v1.z; vh[j*4+3]  = v1.w;
  }

  int kmax = len - w * 12; if (kmax > 12) kmax = 12;
  for (int kk = 0; kk < kmax; kk++){
    int k = w * 12 + kk;
    const u16* akp = ak + (size_t)(k * NB + b) * HDIM + lane * 16;
    us8 a0 = *(const us8*)(akp);
    us8 a1 = *(const us8*)(akp + 8);
    float p = 0.f;
    #pragma unroll
    for (int j = 0; j < 8; j++){
      p += tanh_f(aqr[j]     + bf2f(a0[j])) * vh[j];
      p += tanh_f(aqr[8 + j] + bf2f(a1[j])) * vh[8 + j];
    }
    #pragma unroll
    for (int m = 32; m >= 1; m >>= 1) p += __shfl_xor(p, m);
    if (lane == 0) sc[k] = p;
  }
  __syncthreads();
  float mx = -3.0e38f;
  for (int k = 0; k < len; k++) mx = fmaxf(mx, sc[k]);
  if (t < len) ps[t] = __expf(sc[t] - mx);
  __syncthreads();
  float den = 0.f;
  for (int k = 0; k < len; k++) den += ps[k];
  float rden = __builtin_amdgcn_rcpf(den);

  float c0 = 0.f, c1 = 0.f, c2 = 0.f, c3 = 0.f;
  for (int k = 0; k < len; k++){
    float pk = ps[k];
    ushort4 kv = *(const ushort4*)(keys + (size_t)(k * NB + b) * HDIM + t * 4);
    c0 += pk * bf2f(kv.x); c1 += pk * bf2f(kv.y);
    c2 += pk * bf2f(kv.z); c3 += pk * bf2f(kv.w);
  }
  size_t o = (size_t)(q * NB + b) * HDIM + t * 4;
  out1[o + 0] = c0 * rden;
  out1[o + 1] = c1 * rden;
  out1[o + 2] = c2 * rden;
  out1[o + 3] = c3 * rden;
}

// ---------------- launch ----------------

extern "C" void kernel_launch(void* const* d_in, const int* in_sizes, int n_in,
                              void* d_out, int out_size, void* d_ws, size_t ws_size,
                              hipStream_t stream)
{
  const float* in1  = (const float*)d_in[0];   // input1
  const float* in0  = (const float*)d_in[1];   // input0
  const int*   lens = (const int*)d_in[2];     // input2
  const int*   toks = (const int*)d_in[3];     // input3
  const float* emb  = (const float*)d_in[4];
  const float* Wih  = (const float*)d_in[5];
  const float* Whh  = (const float*)d_in[6];
  const float* bih  = (const float*)d_in[7];
  const float* bhh  = (const float*)d_in[8];
  const float* Wq   = (const float*)d_in[9];
  const float* Wk   = (const float*)d_in[10];
  const float* vatt = (const float*)d_in[11];
  const float* ns   = (const float*)d_in[12];
  const float* nbb  = (const float*)d_in[13];

  char* p = (char*)d_ws;
  u16* x_bf    = (u16*)p;   p += (size_t)2048 * 1024 * 2;   // 4 MB
  u16* keys_bf = (u16*)p;   p += (size_t)3072 * 1024 * 2;   // 6 MB
  u16* hA      = (u16*)p;   p += (size_t)64 * 1024 * 2;
  u16* hB      = (u16*)p;   p += (size_t)64 * 1024 * 2;
  u16* qbuf    = (u16*)p;   p += (size_t)2048 * 1024 * 2;   // 4 MB
  u16* xp      = (u16*)p;   p += (size_t)2048 * 4096 * 2;   // 16 MB (dead after LSTM)
  float* vhat  = (float*)p; p += 1024 * 4;
  float* bsum  = (float*)p; p += 4096 * 4;
  float* nbf   = (float*)p; p += 1024 * 4;
  int* flags   = (int*)p;   p += 4096;                      // 64 flags, 64B apart
  u16* ak      = (u16*)p;   p += (size_t)3072 * 1024 * 2;   // 6 MB
  u16* Wih_bf  = (u16*)p;   p += (size_t)4096 * 1024 * 2;   // 8 MB
  u16* Wq_bf   = (u16*)p;   p += (size_t)1024 * 1024 * 2;   // 2 MB
  u16* Wk_bf   = (u16*)p;   p += (size_t)1024 * 1024 * 2;   // 2 MB
  float* aq    = (float*)xp;   // 8 MB, aliases xp (xp fully consumed before aq GEMM)

  float* out0 = (float*)d_out;
  float* out1 = out0 + (size_t)T_Q * NB * HDIM;

  hipMemsetAsync(flags, 0, 4096, stream);

  conv_f2b<<<4096, 256, 0, stream>>>(Wih, Wih_bf);
  conv_f2b<<<1024, 256, 0, stream>>>(Wq,  Wq_bf);
  conv_f2b<<<1024, 256, 0, stream>>>(Wk,  Wk_bf);
  gather_x<<<2048, 256, 0, stream>>>(toks, emb, x_bf);
  make_keys<<<3072, 256, 0, stream>>>(in1, in0, keys_bf);
  prep_small<<<1, 256, 0, stream>>>(vatt, ns, nbb, vhat, nbf);
  prep_bsum<<<16, 256, 0, stream>>>(bih, bhh, bsum);

  // xp = x * Wih^T + (bih + bhh) : M=2048, N=4096, K=1024 -> bf16
  gemm_bf16<1><<<dim3(64, 32), 256, 0, stream>>>(x_bf, Wih_bf, bsum, xp, 2048, 4096, 1024);
  // ak = keys * Wk^T + norm_bias : M=3072, N=1024, K=1024 -> bf16
  gemm_bf16<1><<<dim3(16, 48), 256, 0, stream>>>(keys_bf, Wk_bf, nbf, ak, 3072, 1024, 1024);

  // all 32 LSTM steps in one persistent kernel (144KB dynamic LDS, 1 block/CU)
  lstm_persistent<<<LSTM_BLOCKS, 512, 147456, stream>>>(Whh, xp, hA, hB, qbuf, out0, flags);

  // aq = q * Wq^T : M=2048, N=1024, K=1024 -> f32 (writes over xp region, now dead)
  gemm_bf16<0><<<dim3(16, 32), 256, 0, stream>>>(qbuf, Wq_bf, nullptr, aq, 2048, 1024, 1024);

  attn_fused<<<2048, 256, 0, stream>>>(aq, ak, vhat, keys_bf, lens, out1);
}

// Round 6
// 337.816 us; speedup vs baseline: 3.4903x; 1.9001x over previous
//
#include <hip/hip_runtime.h>
#include <hip/hip_bf16.h>

typedef unsigned short u16;
typedef __attribute__((ext_vector_type(8))) short bf16x8;
typedef __attribute__((ext_vector_type(8))) unsigned short us8;
typedef __attribute__((ext_vector_type(4))) float f32x4;

#define T_Q 32
#define T_K 48
#define NB 64
#define HDIM 1024
#define MASK_FILL -65504.0f
#define LSTM_BLOCKS 64

__device__ __forceinline__ float bf2f(u16 v){
  union { unsigned u; float f; } x; x.u = ((unsigned)v) << 16; return x.f;
}
__device__ __forceinline__ u16 f2bf(float f){
  union { float f; unsigned u; } x; x.f = f;
  return (u16)((x.u + 0x7FFFu + ((x.u >> 16) & 1u)) >> 16);
}
__device__ __forceinline__ float sigm(float x){
  return __builtin_amdgcn_rcpf(1.f + __expf(-x));
}
__device__ __forceinline__ float tanh_f(float x){
  float e = __expf(2.f * x);
  return fmaf(-2.f, __builtin_amdgcn_rcpf(e + 1.f), 1.f);  // graceful at +/-inf
}

// Cross-XCD coherent sync-path ops (sc0 = bypass L0/L1, sc1 = bypass local L2;
// coherence point = Infinity Cache). Used ONLY for the tiny publish/flag path.
// h DATA loads are normal cached loads against write-once rotating buffers.
__device__ __forceinline__ void st_b32_cc(u16* a, unsigned v){
  asm volatile("global_store_dword %0, %1, off sc0 sc1" :: "v"(a), "v"(v) : "memory");
}
__device__ __forceinline__ void st_flag(int* a, int v){
  asm volatile("global_store_dword %0, %1, off sc0 sc1" :: "v"(a), "v"(v) : "memory");
}
__device__ __forceinline__ int ld_flag(const int* a){
  int r;
  asm volatile("global_load_dword %0, %1, off sc0 sc1\n\ts_waitcnt vmcnt(0)"
               : "=v"(r) : "v"(a) : "memory");
  return r;
}

#define MFMA16(A,B,C) __builtin_amdgcn_mfma_f32_16x16x32_bf16(A,B,C,0,0,0)

// ---------------- prep kernels ----------------

__global__ void conv_f2b(const float* __restrict__ s, u16* __restrict__ d){
  size_t i = ((size_t)blockIdx.x * 256 + threadIdx.x) * 4;
  float4 v = *(const float4*)(s + i);
  ushort4 o; o.x = f2bf(v.x); o.y = f2bf(v.y); o.z = f2bf(v.z); o.w = f2bf(v.w);
  *(ushort4*)(d + i) = o;
}

__global__ void gather_x(const int* __restrict__ tok, const float* __restrict__ emb,
                         u16* __restrict__ x){
  int r = blockIdx.x;                      // r = t*64 + b
  int token = tok[r];
  float4 v = ((const float4*)(emb + (size_t)token * HDIM))[threadIdx.x];
  ushort4 o; o.x = f2bf(v.x); o.y = f2bf(v.y); o.z = f2bf(v.z); o.w = f2bf(v.w);
  ((ushort4*)(x + (size_t)r * HDIM))[threadIdx.x] = o;
}

__global__ void make_keys(const float* __restrict__ a, const float* __restrict__ b,
                          u16* __restrict__ o){
  size_t i = ((size_t)blockIdx.x * 256 + threadIdx.x) * 4;
  float4 va = *(const float4*)(a + i);
  float4 vb = *(const float4*)(b + i);
  ushort4 vo;
  vo.x = f2bf(va.x + vb.x);
  vo.y = f2bf(va.y + vb.y);
  vo.z = f2bf(va.z + vb.z);
  vo.w = f2bf(va.w + vb.w);
  *(ushort4*)(o + i) = vo;
}

__global__ void prep_small(const float* __restrict__ vatt, const float* __restrict__ ns,
                           const float* __restrict__ nb,
                           float* __restrict__ vhat, float* __restrict__ nbias){
  __shared__ float wred[4];
  int t = threadIdx.x, lane = t & 63, w = t >> 6;
  float vv[4]; float s = 0.f;
  #pragma unroll
  for (int j = 0; j < 4; j++){ vv[j] = vatt[t*4 + j]; s += vv[j]*vv[j]; }
  #pragma unroll
  for (int m = 32; m >= 1; m >>= 1) s += __shfl_xor(s, m);
  if (lane == 0) wred[w] = s;
  __syncthreads();
  float tot = wred[0] + wred[1] + wred[2] + wred[3];
  float scale = ns[0] / sqrtf(tot);
  #pragma unroll
  for (int j = 0; j < 4; j++) vhat[t*4 + j] = vv[j] * scale;
  #pragma unroll
  for (int j = 0; j < 4; j++){ int i = t + 256*j; nbias[i] = nb[i]; }
}

__global__ void prep_bsum(const float* __restrict__ bih, const float* __restrict__ bhh,
                          float* __restrict__ bias_sum){
  int i = blockIdx.x * 256 + threadIdx.x;
  bias_sum[i] = bih[i] + bhh[i];
}

// ---------------- generic bf16 GEMM: C[M][N] = A[M][K] * W[N][K]^T + bias ----------------
// OB=1 -> bf16 output, OB=0 -> f32 output.

template<int OB>
__global__ __launch_bounds__(256) void gemm_bf16(
  const u16* __restrict__ A, const u16* __restrict__ W,
  const float* __restrict__ bias, void* __restrict__ Cv,
  int M, int N, int K)
{
  __shared__ __align__(16) u16 As[4][66][8];   // [kc][row][8], kc-stride 1056B
  __shared__ __align__(16) u16 Bs[4][66][8];
  const int t = threadIdx.x;
  const int m0 = blockIdx.y * 64, n0 = blockIdx.x * 64;
  const int lane = t & 63, w = t >> 6;
  const int wm = (w >> 1) * 32, wn = (w & 1) * 32;
  const int lr = lane & 15, g = lane >> 4;
  const int lrow = t >> 2, lkc = t & 3;
  f32x4 acc00 = {0,0,0,0}, acc01 = {0,0,0,0}, acc10 = {0,0,0,0}, acc11 = {0,0,0,0};
  const u16* aptr = A + (size_t)(m0 + lrow) * K + lkc * 8;
  const u16* wptr = W + (size_t)(n0 + lrow) * K + lkc * 8;
  for (int k0 = 0; k0 < K; k0 += 32){
    *(bf16x8*)(&As[lkc][lrow][0]) = *(const bf16x8*)(aptr + k0);
    *(bf16x8*)(&Bs[lkc][lrow][0]) = *(const bf16x8*)(wptr + k0);
    __syncthreads();
    bf16x8 a0 = *(const bf16x8*)(&As[g][wm      + lr][0]);
    bf16x8 a1 = *(const bf16x8*)(&As[g][wm + 16 + lr][0]);
    bf16x8 b0 = *(const bf16x8*)(&Bs[g][wn      + lr][0]);
    bf16x8 b1 = *(const bf16x8*)(&Bs[g][wn + 16 + lr][0]);
    acc00 = MFMA16(a0, b0, acc00);
    acc01 = MFMA16(a0, b1, acc01);
    acc10 = MFMA16(a1, b0, acc10);
    acc11 = MFMA16(a1, b1, acc11);
    __syncthreads();
  }
  // C/D layout: col = lane&15, row = (lane>>4)*4 + reg   [m89-verified]
  const int rb = m0 + wm + g * 4;
  const int cb = n0 + wn + lr;
  float bv0 = bias ? bias[cb]      : 0.f;
  float bv1 = bias ? bias[cb + 16] : 0.f;
  #pragma unroll
  for (int r = 0; r < 4; r++){
    float v00 = acc00[r] + bv0, v01 = acc01[r] + bv1;
    float v10 = acc10[r] + bv0, v11 = acc11[r] + bv1;
    if (OB){
      u16* C = (u16*)Cv;
      C[(size_t)(rb + r)      * N + cb]      = f2bf(v00);
      C[(size_t)(rb + r)      * N + cb + 16] = f2bf(v01);
      C[(size_t)(rb + 16 + r) * N + cb]      = f2bf(v10);
      C[(size_t)(rb + 16 + r) * N + cb + 16] = f2bf(v11);
    } else {
      float* C = (float*)Cv;
      C[(size_t)(rb + r)      * N + cb]      = v00;
      C[(size_t)(rb + r)      * N + cb + 16] = v01;
      C[(size_t)(rb + 16 + r) * N + cb]      = v10;
      C[(size_t)(rb + 16 + r) * N + cb + 16] = v11;
    }
  }
}

// ---------------- persistent LSTM ----------------
// 64 blocks x 512 threads. Block j owns h-cols [j*16, j*16+16) for all 4 gates.
// Whh slice (f32->bf16) resident in LDS; c-state in registers.
// h exchange: ROTATING WRITE-ONCE buffers hsteps[step][j][batch][16] --
//   * block-contiguous 2KB publish region (no cache line shared between writers)
//   * publish via sc0sc1 write-through + vmcnt(0) + per-block flag (r5-proven)
//   * consume via NORMAL CACHED loads (fresh by construction: line written once
//     per launch, demand-fetched only after flag gate) -> L2-shared, no 32MB/step
//     of L2-bypass traffic (r3-r5 bottleneck).

__global__ __launch_bounds__(512, 1) void lstm_persistent(
  const float* __restrict__ Whh, const u16* __restrict__ xp,
  u16* __restrict__ hsteps,
  u16* __restrict__ qbuf, float* __restrict__ out0,
  int* __restrict__ flags)
{
  extern __shared__ char smem[];
  u16*  wlds = (u16*)smem;                    // [4][32][16][32] bf16
  float* gl  = (float*)(smem + 131072);       // [4][64][16] f32

  const int tid = threadIdx.x;
  const int c0 = blockIdx.x * 16;
  const int lane = tid & 63, w = tid >> 6;    // 8 waves
  const int gate = w & 3, msub = w >> 2;      // wave -> (gate, m-half)
  const int lr = lane & 15, g = lane >> 4;

  // ---- one-time: Whh slice f32 -> bf16 -> LDS ----
  #pragma unroll
  for (int i = 0; i < 16; i++){
    int e = (i * 512 + tid) * 8;               // element in 64x1024 slice
    int R = e >> 10, k = e & 1023;
    int gg = R >> 4, rr = R & 15, tt = k >> 5, kk = k & 31;
    const float* src = Whh + (size_t)((gg << 10) + c0 + rr) * 1024 + k;
    float4 v0 = *(const float4*)(src);
    float4 v1 = *(const float4*)(src + 4);
    u16* dst = wlds + (((gg * 32 + tt) * 16 + rr) * 32 + kk);
    ushort4 o0, o1;
    o0.x = f2bf(v0.x); o0.y = f2bf(v0.y); o0.z = f2bf(v0.z); o0.w = f2bf(v0.w);
    o1.x = f2bf(v1.x); o1.y = f2bf(v1.y); o1.z = f2bf(v1.z); o1.w = f2bf(v1.w);
    *(ushort4*)dst = o0; *(ushort4*)(dst + 4) = o1;
  }
  __syncthreads();

  // pointwise ownership: 2 cells/thread
  const int pb = (tid * 2) >> 4;               // batch 0..63
  const int pc = (tid * 2) & 15;               // col pair base (even)
  float c_state0 = 0.f, c_state1 = 0.f;

  const int arow = msub * 32 + lr;             // batch rows for this wave's m-tiles
  // h layout addressing: elem(step, row, k) = step*65536 + (k>>4)*1024 + row*16 + (k&15)
  const int jc = g >> 1;                       // (k0>>4) parity from g
  const int cc = (g & 1) * 8;                  // col offset within 16-col group

  #pragma unroll 1
  for (int step = 0; step < T_Q; step++){
    f32x4 acc0 = {0,0,0,0}, acc1 = {0,0,0,0};

    if (step > 0){
      // ---- gate: wait until all blocks published h_{step-1} ----
      if (w == 0){
        const int* fp = flags + lane * 16;
        for (;;){
          int f = ld_flag(fp);
          if (__ballot(f >= step) == ~0ull) break;
          __builtin_amdgcn_s_sleep(1);
        }
      }
      __syncthreads();

      const u16* hb = hsteps + (size_t)(step - 1) * 65536;
      const u16* pa0 = hb + (size_t)jc * 1024 + (size_t)arow * 16 + cc;
      const u16* pa1 = pa0 + 16 * 16;          // rows arow+16
      bf16x8 a0[8], a1[8];
      #pragma unroll
      for (int p = 0; p < 8; p++){
        a0[p] = *(const bf16x8*)(pa0 + p * 2048);
        a1[p] = *(const bf16x8*)(pa1 + p * 2048);
      }
      #pragma unroll
      for (int t = 0; t < 32; t++){
        bf16x8 bfr = *(const bf16x8*)(wlds + ((size_t)(gate * 32 + t) * 16 + lr) * 32 + g * 8);
        acc0 = MFMA16(a0[t & 7], bfr, acc0);
        acc1 = MFMA16(a1[t & 7], bfr, acc1);
        if (t < 24){
          a0[t & 7] = *(const bf16x8*)(pa0 + (t + 8) * 2048);
          a1[t & 7] = *(const bf16x8*)(pa1 + (t + 8) * 2048);
        }
      }
    }

    // this step's xp slice for the pointwise
    const u16* xr = xp + ((size_t)(step * NB + pb)) * 4096 + c0 + pc;
    unsigned xw0 = *(const unsigned*)(xr);
    unsigned xw1 = *(const unsigned*)(xr + 1024);
    unsigned xw2 = *(const unsigned*)(xr + 2048);
    unsigned xw3 = *(const unsigned*)(xr + 3072);

    // gate preacts -> LDS exchange. C/D: col=lane&15, row=(lane>>4)*4+reg
    #pragma unroll
    for (int r = 0; r < 4; r++){
      gl[(gate * 64 + msub * 32 +      g * 4 + r) * 16 + lr] = acc0[r];
      gl[(gate * 64 + msub * 32 + 16 + g * 4 + r) * 16 + lr] = acc1[r];
    }
    __syncthreads();

    // pointwise: 2 cells (pb, pc) (pb, pc+1)
    float hout0, hout1; u16 hb0, hb1;
    {
      float ig = gl[(0 * 64 + pb) * 16 + pc] + bf2f((u16)(xw0 & 0xFFFF));
      float fg = gl[(1 * 64 + pb) * 16 + pc] + bf2f((u16)(xw1 & 0xFFFF));
      float gg = gl[(2 * 64 + pb) * 16 + pc] + bf2f((u16)(xw2 & 0xFFFF));
      float og = gl[(3 * 64 + pb) * 16 + pc] + bf2f((u16)(xw3 & 0xFFFF));
      float cn = sigm(fg) * c_state0 + sigm(ig) * tanh_f(gg);
      c_state0 = cn;
      hout0 = sigm(og) * tanh_f(cn); hb0 = f2bf(hout0);
    }
    {
      float ig = gl[(0 * 64 + pb) * 16 + pc + 1] + bf2f((u16)(xw0 >> 16));
      float fg = gl[(1 * 64 + pb) * 16 + pc + 1] + bf2f((u16)(xw1 >> 16));
      float gg = gl[(2 * 64 + pb) * 16 + pc + 1] + bf2f((u16)(xw2 >> 16));
      float og = gl[(3 * 64 + pb) * 16 + pc + 1] + bf2f((u16)(xw3 >> 16));
      float cn = sigm(fg) * c_state1 + sigm(ig) * tanh_f(gg);
      c_state1 = cn;
      hout1 = sigm(og) * tanh_f(cn); hb1 = f2bf(hout1);
    }

    if (step < T_Q - 1){
      // publish h_step into block-contiguous region, then flag. One dword/thread.
      u16* hw = hsteps + (size_t)step * 65536 + (size_t)blockIdx.x * 1024 + pb * 16 + pc;
      unsigned hpack = (unsigned)hb0 | ((unsigned)hb1 << 16);
      st_b32_cc(hw, hpack);
      asm volatile("s_waitcnt vmcnt(0)" ::: "memory");
      __syncthreads();                          // whole block's h is at L3
      if (tid == 0) st_flag(flags + blockIdx.x * 16, step + 1);
    }

    ushort2 hh; hh.x = hb0; hh.y = hb1;
    *(ushort2*)(qbuf + ((size_t)pb * T_Q + step) * HDIM + c0 + pc) = hh;
    float2 ho; ho.x = hout0; ho.y = hout1;
    *(float2*)(out0 + ((size_t)(step * NB + pb)) * HDIM + c0 + pc) = ho;
  }
}

// ---------------- fused attention: scores -> softmax -> context ----------------
// block per (b,q). wave w handles keys k in [w*12, min(len,w*12+12)). len-bounded:
// masked keys contribute exactly 0 to softmax/context, so skip their tanh work.

__global__ __launch_bounds__(256) void attn_fused(
  const float* __restrict__ aq, const u16* __restrict__ ak,
  const float* __restrict__ vhat, const u16* __restrict__ keys,
  const int* __restrict__ lens, float* __restrict__ out1)
{
  int b = blockIdx.x >> 5, q = blockIdx.x & 31;
  int t = threadIdx.x, lane = t & 63, w = t >> 6;
  __shared__ float sc[T_K];
  __shared__ float ps[T_K];
  int len = lens[b];
  float aqr[16], vh[16];
  const float* aqp = aq + (size_t)(b * T_Q + q) * HDIM + lane * 16;
  const float* vp  = vhat + lane * 16;
  #pragma unroll
  for (int j = 0; j < 4; j++){
    float4 v0 = ((const float4*)aqp)[j];
    float4 v1 = ((const float4*)vp)[j];
    aqr[j*4+0] = v0.x; aqr[j*4+1] = v0.y; aqr[j*4+2] = v0.z; aqr[j*4+3] = v0.w;
    vh[j*4+0]  = v1.x; vh[j*4+1]  = v1.y; vh[j*4+2]  = v1.z; vh[j*4+3]  = v1.w;
  }

  int kmax = len - w * 12; if (kmax > 12) kmax = 12;
  for (int kk = 0; kk < kmax; kk++){
    int k = w * 12 + kk;
    const u16* akp = ak + (size_t)(k * NB + b) * HDIM + lane * 16;
    us8 a0 = *(const us8*)(akp);
    us8 a1 = *(const us8*)(akp + 8);
    float p = 0.f;
    #pragma unroll
    for (int j = 0; j < 8; j++){
      p += tanh_f(aqr[j]     + bf2f(a0[j])) * vh[j];
      p += tanh_f(aqr[8 + j] + bf2f(a1[j])) * vh[8 + j];
    }
    #pragma unroll
    for (int m = 32; m >= 1; m >>= 1) p += __shfl_xor(p, m);
    if (lane == 0) sc[k] = p;
  }
  __syncthreads();
  float mx = -3.0e38f;
  for (int k = 0; k < len; k++) mx = fmaxf(mx, sc[k]);
  if (t < len) ps[t] = __expf(sc[t] - mx);
  __syncthreads();
  float den = 0.f;
  for (int k = 0; k < len; k++) den += ps[k];
  float rden = __builtin_amdgcn_rcpf(den);

  float c0 = 0.f, c1 = 0.f, c2 = 0.f, c3 = 0.f;
  for (int k = 0; k < len; k++){
    float pk = ps[k];
    ushort4 kv = *(const ushort4*)(keys + (size_t)(k * NB + b) * HDIM + t * 4);
    c0 += pk * bf2f(kv.x); c1 += pk * bf2f(kv.y);
    c2 += pk * bf2f(kv.z); c3 += pk * bf2f(kv.w);
  }
  size_t o = (size_t)(q * NB + b) * HDIM + t * 4;
  out1[o + 0] = c0 * rden;
  out1[o + 1] = c1 * rden;
  out1[o + 2] = c2 * rden;
  out1[o + 3] = c3 * rden;
}

// ---------------- launch ----------------

extern "C" void kernel_launch(void* const* d_in, const int* in_sizes, int n_in,
                              void* d_out, int out_size, void* d_ws, size_t ws_size,
                              hipStream_t stream)
{
  const float* in1  = (const float*)d_in[0];   // input1
  const float* in0  = (const float*)d_in[1];   // input0
  const int*   lens = (const int*)d_in[2];     // input2
  const int*   toks = (const int*)d_in[3];     // input3
  const float* emb  = (const float*)d_in[4];
  const float* Wih  = (const float*)d_in[5];
  const float* Whh  = (const float*)d_in[6];
  const float* bih  = (const float*)d_in[7];
  const float* bhh  = (const float*)d_in[8];
  const float* Wq   = (const float*)d_in[9];
  const float* Wk   = (const float*)d_in[10];
  const float* vatt = (const float*)d_in[11];
  const float* ns   = (const float*)d_in[12];
  const float* nbb  = (const float*)d_in[13];

  char* p = (char*)d_ws;
  u16* x_bf    = (u16*)p;   p += (size_t)2048 * 1024 * 2;   // 4 MB
  u16* keys_bf = (u16*)p;   p += (size_t)3072 * 1024 * 2;   // 6 MB
  u16* hsteps  = (u16*)p;   p += (size_t)32 * 65536 * 2;    // 4 MB rotating h
  u16* qbuf    = (u16*)p;   p += (size_t)2048 * 1024 * 2;   // 4 MB
  u16* xp      = (u16*)p;   p += (size_t)2048 * 4096 * 2;   // 16 MB (dead after LSTM)
  float* vhat  = (float*)p; p += 1024 * 4;
  float* bsum  = (float*)p; p += 4096 * 4;
  float* nbf   = (float*)p; p += 1024 * 4;
  int* flags   = (int*)p;   p += 4096;                      // 64 flags, 64B apart
  u16* ak      = (u16*)p;   p += (size_t)3072 * 1024 * 2;   // 6 MB
  u16* Wih_bf  = (u16*)p;   p += (size_t)4096 * 1024 * 2;   // 8 MB
  u16* Wq_bf   = (u16*)p;   p += (size_t)1024 * 1024 * 2;   // 2 MB
  u16* Wk_bf   = (u16*)p;   p += (size_t)1024 * 1024 * 2;   // 2 MB
  float* aq    = (float*)xp;   // 8 MB, aliases xp (xp fully consumed before aq GEMM)

  float* out0 = (float*)d_out;
  float* out1 = out0 + (size_t)T_Q * NB * HDIM;

  hipMemsetAsync(flags, 0, 4096, stream);

  conv_f2b<<<4096, 256, 0, stream>>>(Wih, Wih_bf);
  conv_f2b<<<1024, 256, 0, stream>>>(Wq,  Wq_bf);
  conv_f2b<<<1024, 256, 0, stream>>>(Wk,  Wk_bf);
  gather_x<<<2048, 256, 0, stream>>>(toks, emb, x_bf);
  make_keys<<<3072, 256, 0, stream>>>(in1, in0, keys_bf);
  prep_small<<<1, 256, 0, stream>>>(vatt, ns, nbb, vhat, nbf);
  prep_bsum<<<16, 256, 0, stream>>>(bih, bhh, bsum);

  // xp = x * Wih^T + (bih + bhh) : M=2048, N=4096, K=1024 -> bf16
  gemm_bf16<1><<<dim3(64, 32), 256, 0, stream>>>(x_bf, Wih_bf, bsum, xp, 2048, 4096, 1024);
  // ak = keys * Wk^T + norm_bias : M=3072, N=1024, K=1024 -> bf16
  gemm_bf16<1><<<dim3(16, 48), 256, 0, stream>>>(keys_bf, Wk_bf, nbf, ak, 3072, 1024, 1024);

  // all 32 LSTM steps in one persistent kernel (144KB dynamic LDS, 1 block/CU)
  lstm_persistent<<<LSTM_BLOCKS, 512, 147456, stream>>>(Whh, xp, hsteps, qbuf, out0, flags);

  // aq = q * Wq^T : M=2048, N=1024, K=1024 -> f32 (writes over xp region, now dead)
  gemm_bf16<0><<<dim3(16, 32), 256, 0, stream>>>(qbuf, Wq_bf, nullptr, aq, 2048, 1024, 1024);

  attn_fused<<<2048, 256, 0, stream>>>(aq, ak, vhat, keys_bf, lens, out1);
}